// Round 3
// baseline (5239.778 us; speedup 1.0000x reference)
//
#include <hip/hip_runtime.h>
#include <math.h>

constexpr int NLAYER = 12;
constexpr int H = 768;
constexpr int NH = 12;
constexpr int DH = 64;
constexpr int T = 512;
constexpr int B = 4;
constexpr int K = 21;
constexpr int BT = B * T;
constexpr float NEGB = -10000.0f;
constexpr float LNEPS = 1e-12f;
constexpr float INV_SQRT_DH = 0.125f;

typedef __attribute__((ext_vector_type(8))) short bf16x8;
typedef __attribute__((ext_vector_type(4))) float f32x4;
typedef __attribute__((ext_vector_type(4))) unsigned short u16x4;

// ---------------- helpers ----------------
__device__ __forceinline__ float wave_sum_f(float v) {
#pragma unroll
  for (int off = 32; off > 0; off >>= 1) v += __shfl_xor(v, off);
  return v;
}
__device__ __forceinline__ int wave_sum_i(int v) {
#pragma unroll
  for (int off = 32; off > 0; off >>= 1) v += __shfl_xor(v, off);
  return v;
}
__device__ __forceinline__ float readlane_f(float v, int i) {
  return __uint_as_float(__builtin_amdgcn_readlane(__float_as_uint(v), i));
}
__device__ __forceinline__ unsigned short f32_bf16_rn(float x) {
  unsigned int u = __float_as_uint(x);
  u += 0x7fffu + ((u >> 16) & 1u);
  return (unsigned short)(u >> 16);
}
__device__ __forceinline__ void split_bf16(float x, unsigned short& h, unsigned short& l) {
  h = f32_bf16_rn(x);
  float hf = __uint_as_float((unsigned int)h << 16);
  l = f32_bf16_rn(x - hf);
}
__device__ __forceinline__ void block_reduce_sum2(float& s, float& q) {
  __shared__ float red[8];
  s = wave_sum_f(s);
  q = wave_sum_f(q);
  int lane = threadIdx.x & 63, wid = threadIdx.x >> 6;
  if (lane == 0) { red[wid] = s; red[4 + wid] = q; }
  __syncthreads();
  s = red[0] + red[1] + red[2] + red[3];
  q = red[4] + red[5] + red[6] + red[7];
}

// ---------------- embedding + LN (emits f32 h and split bf16) ----------------
__global__ __launch_bounds__(256) void embed_ln_kernel(
    const int* __restrict__ ids, const float* __restrict__ wemb,
    const float* __restrict__ pemb, const float* __restrict__ temb,
    const float* __restrict__ g, const float* __restrict__ bta,
    float* __restrict__ h, unsigned short* __restrict__ hh,
    unsigned short* __restrict__ hl) {
  int row = blockIdx.x;
  int t = row % T;
  int id = ids[row];
  const float* wp = wemb + (size_t)id * H;
  const float* pp = pemb + (size_t)t * H;
  float x[3];
  float s = 0.f, q = 0.f;
#pragma unroll
  for (int i = 0; i < 3; i++) {
    int c = threadIdx.x + i * 256;
    x[i] = wp[c] + pp[c] + temb[c];
    s += x[i];
    q += x[i] * x[i];
  }
  block_reduce_sum2(s, q);
  float mean = s * (1.0f / H);
  float var = q * (1.0f / H) - mean * mean;
  float inv = rsqrtf(var + LNEPS);
#pragma unroll
  for (int i = 0; i < 3; i++) {
    int c = threadIdx.x + i * 256;
    float y = (x[i] - mean) * inv * g[c] + bta[c];
    h[(size_t)row * H + c] = y;
    unsigned short yh, yl;
    split_bf16(y, yh, yl);
    hh[(size_t)row * H + c] = yh;
    hl[(size_t)row * H + c] = yl;
  }
}

// ---------------- residual add + LN (emits f32 h and split bf16) ----------------
__global__ __launch_bounds__(256) void add_ln_kernel(
    float* __restrict__ h, const float* __restrict__ add,
    const float* __restrict__ g, const float* __restrict__ bta,
    unsigned short* __restrict__ hh, unsigned short* __restrict__ hl) {
  int row = blockIdx.x;
  size_t base = (size_t)row * H;
  float x[3];
  float s = 0.f, q = 0.f;
#pragma unroll
  for (int i = 0; i < 3; i++) {
    int c = threadIdx.x + i * 256;
    x[i] = h[base + c] + add[base + c];
    s += x[i];
    q += x[i] * x[i];
  }
  block_reduce_sum2(s, q);
  float mean = s * (1.0f / H);
  float var = q * (1.0f / H) - mean * mean;
  float inv = rsqrtf(var + LNEPS);
#pragma unroll
  for (int i = 0; i < 3; i++) {
    int c = threadIdx.x + i * 256;
    float y = (x[i] - mean) * inv * g[c] + bta[c];
    h[base + c] = y;
    unsigned short yh, yl;
    split_bf16(y, yh, yl);
    hh[base + c] = yh;
    hl[base + c] = yl;
  }
}

// ---------------- per-layer weight transpose + split ----------------
// W[Kd][N] f32 -> Wth/Wtl [N][Kd] bf16 at per-weight offsets.
__global__ __launch_bounds__(256) void wconv_kernel(
    const float* __restrict__ w0, const float* __restrict__ w1,
    const float* __restrict__ w2, const float* __restrict__ w3,
    unsigned short* __restrict__ Wth, unsigned short* __restrict__ Wtl) {
  __shared__ float tile[32][33];
  int bid = blockIdx.x;
  const float* src;
  int Kd, N, tk, tn;
  size_t off;
  if (bid < 1728) {            // Wqkv 768x2304
    src = w0; Kd = 768; N = 2304; tk = bid / 72; tn = bid % 72; off = 0;
  } else if (bid < 2304) {     // Wo 768x768
    int t2 = bid - 1728; src = w1; Kd = 768; N = 768; tk = t2 / 24; tn = t2 % 24;
    off = 1769472;
  } else if (bid < 4608) {     // W1 768x3072
    int t2 = bid - 2304; src = w2; Kd = 768; N = 3072; tk = t2 / 96; tn = t2 % 96;
    off = 2359296;
  } else {                     // W2 3072x768
    int t2 = bid - 4608; src = w3; Kd = 3072; N = 768; tk = t2 / 24; tn = t2 % 24;
    off = 4718592;
  }
  int tid = threadIdx.x;
  int k0 = tk * 32, n0 = tn * 32;
  int r = tid >> 3, c = (tid & 7) * 4;
  float4 v = *(const float4*)(src + (size_t)(k0 + r) * N + n0 + c);
  tile[r][c + 0] = v.x; tile[r][c + 1] = v.y; tile[r][c + 2] = v.z; tile[r][c + 3] = v.w;
  __syncthreads();
  // out element (n0+r, k0+c+q) = W[k0+c+q][n0+r] = tile[c+q][r]
  u16x4 hv, lv;
#pragma unroll
  for (int q2 = 0; q2 < 4; q2++) {
    unsigned short sh, sl;
    split_bf16(tile[c + q2][r], sh, sl);
    hv[q2] = sh; lv[q2] = sl;
  }
  size_t dst = off + (size_t)(n0 + r) * Kd + k0 + c;
  *(u16x4*)(Wth + dst) = hv;
  *(u16x4*)(Wtl + dst) = lv;
}

// ---------------- f32 -> split bf16 pass (ffn1 output) ----------------
__global__ __launch_bounds__(256) void fsplit_kernel(
    const float* __restrict__ x, unsigned short* __restrict__ xh,
    unsigned short* __restrict__ xl, int n4) {
  int i = blockIdx.x * 256 + threadIdx.x;
  if (i >= n4) return;
  float4 v = ((const float4*)x)[i];
  u16x4 hv, lv;
  unsigned short sh, sl;
  split_bf16(v.x, sh, sl); hv[0] = sh; lv[0] = sl;
  split_bf16(v.y, sh, sl); hv[1] = sh; lv[1] = sl;
  split_bf16(v.z, sh, sl); hv[2] = sh; lv[2] = sl;
  split_bf16(v.w, sh, sl); hv[3] = sh; lv[3] = sl;
  ((u16x4*)xh)[i] = hv;
  ((u16x4*)xl)[i] = lv;
}

// ---------------- bf16 3-term MFMA GEMM (pre-split operands) ----------------
// C[M,N] = A @ W + bias ; A split (Ah,Al) [M][Kd] bf16 ; W^T split (Wth,Wtl) [N][Kd] bf16
// 128x128 tile, BK=32, 4 waves (2x2), per-wave 64x64, global_load_lds staging.
template <bool GELU>
__global__ __launch_bounds__(256) void gemm_bf3_kernel(
    const unsigned short* __restrict__ Ah, const unsigned short* __restrict__ Al,
    const unsigned short* __restrict__ Wth, const unsigned short* __restrict__ Wtl,
    const float* __restrict__ bias, float* __restrict__ C, int N, int Kd) {
  __shared__ short lds_s[4 * 4096];  // Ah|Al|Wh|Wl tiles, each 128 rows x 32 bf16 (64B rows)
  int tid = threadIdx.x;
  int lane = tid & 63, wid = tid >> 6;
  int wr = wid >> 1, wc = wid & 1;
  int bm = blockIdx.y * 128, bn = blockIdx.x * 128;
  f32x4 acc[4][4] = {};

  const unsigned short* bases[4] = {Ah, Al, Wth, Wtl};
  const unsigned short* base = bases[wid];
  int rowbase = (wid >= 2) ? bn : bm;
  int lrow = lane >> 2, lslot = lane & 3;

  for (int k0 = 0; k0 < Kd; k0 += 32) {
#pragma unroll
    for (int c = 0; c < 8; c++) {
      int row = c * 16 + lrow;
      const unsigned short* src = base + (size_t)(rowbase + row) * Kd + k0 + lslot * 8;
      char* dst = ((char*)lds_s) + wid * 8192 + c * 1024 + lane * 16;
      __builtin_amdgcn_global_load_lds(
          (const __attribute__((address_space(1))) void*)src,
          (__attribute__((address_space(3))) void*)dst, 16, 0, 0);
    }
    __syncthreads();
    int lr = lane & 15, lg = lane >> 4;
    bf16x8 af_h[4], af_l[4], wf_h[4], wf_l[4];
#pragma unroll
    for (int i = 0; i < 4; i++) {
      int e = (wr * 64 + i * 16 + lr) * 32 + lg * 8;
      af_h[i] = *(const bf16x8*)&lds_s[e];
      af_l[i] = *(const bf16x8*)&lds_s[4096 + e];
    }
#pragma unroll
    for (int j = 0; j < 4; j++) {
      int e = (wc * 64 + j * 16 + lr) * 32 + lg * 8;
      wf_h[j] = *(const bf16x8*)&lds_s[8192 + e];
      wf_l[j] = *(const bf16x8*)&lds_s[12288 + e];
    }
#pragma unroll
    for (int i = 0; i < 4; i++)
#pragma unroll
      for (int j = 0; j < 4; j++) {
        acc[i][j] = __builtin_amdgcn_mfma_f32_16x16x32_bf16(af_h[i], wf_h[j], acc[i][j], 0, 0, 0);
        acc[i][j] = __builtin_amdgcn_mfma_f32_16x16x32_bf16(af_l[i], wf_h[j], acc[i][j], 0, 0, 0);
        acc[i][j] = __builtin_amdgcn_mfma_f32_16x16x32_bf16(af_h[i], wf_l[j], acc[i][j], 0, 0, 0);
      }
    __syncthreads();
  }
  int lr = lane & 15, lg = lane >> 4;
#pragma unroll
  for (int i = 0; i < 4; i++) {
#pragma unroll
    for (int j = 0; j < 4; j++) {
      int row = bm + wr * 64 + i * 16 + lg * 4;
      int col = bn + wc * 64 + j * 16 + lr;
      float bv = bias[col];
#pragma unroll
      for (int r = 0; r < 4; r++) {
        float v = acc[i][j][r] + bv;
        if (GELU) v = 0.5f * v * (1.0f + erff(v * 0.70710678118654752f));
        C[(size_t)(row + r) * N + col] = v;
      }
    }
  }
}

// ---------------- S = Q K^T * scale + mask bias ----------------
__global__ __launch_bounds__(256) void qk_kernel(
    const float* __restrict__ qkv, const int* __restrict__ mask,
    float* __restrict__ S) {
  int bh = blockIdx.z;
  int b = bh / NH, hh = bh % NH;
  int i0 = blockIdx.y * 64, j0 = blockIdx.x * 64;
  __shared__ float Qs[64][64];
  __shared__ float Ks[64][64];
  int tid = threadIdx.x;
  int r = tid >> 2;
  int cseg = (tid & 3) * 16;
  const float* qbase = qkv + (size_t)(b * T + i0 + r) * (3 * H) + hh * DH;
  const float* kbase = qkv + (size_t)(b * T + j0 + r) * (3 * H) + H + hh * DH;
#pragma unroll
  for (int ss = 0; ss < 4; ss++) {
    int c = cseg + ss * 4;
    float4 qa = *(const float4*)(qbase + c);
    float4 ka = *(const float4*)(kbase + c);
    Qs[c + 0][r] = qa.x; Qs[c + 1][r] = qa.y; Qs[c + 2][r] = qa.z; Qs[c + 3][r] = qa.w;
    Ks[c + 0][r] = ka.x; Ks[c + 1][r] = ka.y; Ks[c + 2][r] = ka.z; Ks[c + 3][r] = ka.w;
  }
  __syncthreads();
  int tx = tid & 15, ty = tid >> 4;
  float acc[4][4] = {};
#pragma unroll 4
  for (int d = 0; d < 64; d++) {
    float a_[4], b_[4];
    *(float4*)a_ = *(const float4*)&Qs[d][ty * 4];
    *(float4*)b_ = *(const float4*)&Ks[d][tx * 4];
#pragma unroll
    for (int i = 0; i < 4; i++)
#pragma unroll
      for (int j = 0; j < 4; j++)
        acc[i][j] = fmaf(a_[i], b_[j], acc[i][j]);
  }
  float bj[4];
#pragma unroll
  for (int q = 0; q < 4; q++)
    bj[q] = (1.0f - (float)mask[b * T + j0 + tx * 4 + q]) * NEGB;
#pragma unroll
  for (int i = 0; i < 4; i++) {
    int gi = i0 + ty * 4 + i;
    int gj = j0 + tx * 4;
    float4 o;
    o.x = acc[i][0] * INV_SQRT_DH + bj[0];
    o.y = acc[i][1] * INV_SQRT_DH + bj[1];
    o.z = acc[i][2] * INV_SQRT_DH + bj[2];
    o.w = acc[i][3] * INV_SQRT_DH + bj[3];
    *(float4*)(S + ((size_t)bh * T + gi) * T + gj) = o;
  }
}

// ---------------- row softmax ----------------
__global__ __launch_bounds__(128) void softmax_kernel(float* __restrict__ S) {
  size_t row = blockIdx.x;
  float* p = S + row * T;
  int tid = threadIdx.x;
  float4 v = *(float4*)(p + tid * 4);
  float m = fmaxf(fmaxf(v.x, v.y), fmaxf(v.z, v.w));
#pragma unroll
  for (int off = 32; off > 0; off >>= 1) m = fmaxf(m, __shfl_xor(m, off));
  __shared__ float redm[2];
  __shared__ float reds[2];
  int wid = tid >> 6;
  if ((tid & 63) == 0) redm[wid] = m;
  __syncthreads();
  m = fmaxf(redm[0], redm[1]);
  v.x = __expf(v.x - m);
  v.y = __expf(v.y - m);
  v.z = __expf(v.z - m);
  v.w = __expf(v.w - m);
  float s = v.x + v.y + v.z + v.w;
  s = wave_sum_f(s);
  if ((tid & 63) == 0) reds[wid] = s;
  __syncthreads();
  s = reds[0] + reds[1];
  float inv = 1.0f / s;
  v.x *= inv; v.y *= inv; v.z *= inv; v.w *= inv;
  *(float4*)(p + tid * 4) = v;
}

// ---------------- ctx = P * V (emits split bf16 ctx) ----------------
__global__ __launch_bounds__(256) void pv_kernel(
    const float* __restrict__ S, const float* __restrict__ qkv,
    unsigned short* __restrict__ cth, unsigned short* __restrict__ ctl) {
  int bh = blockIdx.y;
  int b = bh / NH, hh = bh % NH;
  int i0 = blockIdx.x * 64;
  __shared__ float Ps[64][68];
  __shared__ float Vs[64][64];
  int tid = threadIdx.x;
  int r = tid >> 2;
  int cseg = (tid & 3) * 16;
  int tx = tid & 15, ty = tid >> 4;
  float acc[4][4] = {};
  const float* srow = S + ((size_t)bh * T + i0 + r) * T;
  const float* vbase = qkv + (size_t)(b * T) * (3 * H) + 2 * H + hh * DH;
  for (int k0 = 0; k0 < T; k0 += 64) {
    __syncthreads();
#pragma unroll
    for (int ss = 0; ss < 4; ss++) {
      int c = cseg + ss * 4;
      *(float4*)&Ps[r][c] = *(const float4*)(srow + k0 + c);
      *(float4*)&Vs[r][c] = *(const float4*)(vbase + (size_t)(k0 + r) * (3 * H) + c);
    }
    __syncthreads();
#pragma unroll
    for (int kk = 0; kk < 64; kk += 4) {
      float p_[4][4], v_[4][4];
#pragma unroll
      for (int i = 0; i < 4; i++)
        *(float4*)p_[i] = *(const float4*)&Ps[ty * 4 + i][kk];
#pragma unroll
      for (int s = 0; s < 4; s++)
        *(float4*)v_[s] = *(const float4*)&Vs[kk + s][tx * 4];
#pragma unroll
      for (int i = 0; i < 4; i++)
#pragma unroll
        for (int s = 0; s < 4; s++)
#pragma unroll
          for (int j = 0; j < 4; j++)
            acc[i][j] = fmaf(p_[i][s], v_[s][j], acc[i][j]);
    }
  }
#pragma unroll
  for (int i = 0; i < 4; i++) {
    int gi = i0 + ty * 4 + i;
    size_t idx = (size_t)(b * T + gi) * H + hh * DH + tx * 4;
    u16x4 hv, lv;
#pragma unroll
    for (int j = 0; j < 4; j++) {
      unsigned short sh, sl;
      split_bf16(acc[i][j], sh, sl);
      hv[j] = sh; lv[j] = sl;
    }
    *(u16x4*)(cth + idx) = hv;
    *(u16x4*)(ctl + idx) = lv;
  }
}

// ---------------- classifier ----------------
__global__ __launch_bounds__(256) void classifier_kernel(
    const float* __restrict__ h, const float* __restrict__ Wc,
    const float* __restrict__ bc, float* __restrict__ em) {
  int id = blockIdx.x * 256 + threadIdx.x;
  if (id >= BT * K) return;
  int row = id / K, k = id % K;
  float acc = bc[k];
  const float* hr = h + (size_t)row * H;
  for (int d = 0; d < H; d++) acc = fmaf(hr[d], Wc[d * K + k], acc);
  em[id] = acc;
}

// ---------------- fused CRF nll + viterbi ----------------
__global__ __launch_bounds__(64) void crf_fused_kernel(
    const float* __restrict__ em, const int* __restrict__ labels,
    const int* __restrict__ mask, const float* __restrict__ start,
    const float* __restrict__ endv, const float* __restrict__ trans,
    float* __restrict__ parts, float* __restrict__ outdec) {
  __shared__ float em_s[T * K];
  __shared__ int mask_s[T];
  __shared__ unsigned char hist_s[(T - 1) * K];
  __shared__ float sc_s[32];
  int b = blockIdx.x & 3;
  int role = blockIdx.x >> 2;
  int j = threadIdx.x;
  const float* eb = em + (size_t)b * T * K;
  for (int i = j; i < T * K / 4; i += 64)
    ((float4*)em_s)[i] = ((const float4*)eb)[i];
  for (int i = j; i < T; i += 64) mask_s[i] = mask[b * T + i];
  __syncthreads();
  bool act = (j < K);
  float tr[K];
#pragma unroll
  for (int i = 0; i < K; i++) tr[i] = act ? trans[i * K + j] : 0.f;

  if (role == 0) {
    // ---- numerator ----
    const int* tb = labels + b * T;
    float numloc = 0.f;
    int cnt = 0;
    for (int t = j; t < T; t += 64) {
      cnt += mask_s[t];
      if (t >= 1 && mask_s[t]) {
        int tp = tb[t - 1], tc = tb[t];
        numloc += trans[tp * K + tc] + em_s[t * K + tc];
      }
    }
    float num = wave_sum_f(numloc);
    int cnttot = wave_sum_i(cnt);
    // ---- forward recursion via exp-factorization + readlane ----
    float etr[K];
#pragma unroll
    for (int i = 0; i < K; i++) etr[i] = __expf(tr[i]);
    float alpha = act ? (start[j] + em_s[j]) : 0.f;
    for (int t = 1; t < T; t++) {
      if (!mask_s[t]) continue;
      float m0 = readlane_f(alpha, 0);
      float e = __expf(alpha - m0);
      float p[K];
#pragma unroll
      for (int i = 0; i < K; i++) p[i] = readlane_f(e, i) * etr[i];
#pragma unroll
      for (int s = 1; s < K; s <<= 1) {
#pragma unroll
        for (int i = 0; i + s < K; i += 2 * s) p[i] += p[i + s];
      }
      float nxt = __logf(p[0]) + m0 + (act ? em_s[t * K + j] : 0.f);
      if (act) alpha = nxt;
    }
    float aj = act ? (alpha + endv[j]) : -3.0e38f;
    float mm = aj;
#pragma unroll
    for (int off = 32; off > 0; off >>= 1) mm = fmaxf(mm, __shfl_xor(mm, off));
    float e2 = act ? __expf(aj - mm) : 0.f;
    float s2 = wave_sum_f(e2);
    float den = __logf(s2) + mm;
    if (j == 0) {
      int tag0 = tb[0];
      int lastidx = cnttot - 1;
      float numtot = num + start[tag0] + em_s[tag0] + endv[tb[lastidx]];
      parts[b] = numtot - den;
    }
  } else {
    // ---- Viterbi ----
    float score = act ? (start[j] + em_s[j]) : 0.f;
    for (int t = 1; t < T; t++) {
      int m = mask_s[t];
      if (m) {
        float cv[K];
        int ci[K];
#pragma unroll
        for (int i = 0; i < K; i++) {
          cv[i] = readlane_f(score, i) + tr[i];
          ci[i] = i;
        }
#pragma unroll
        for (int s = 1; s < K; s <<= 1) {
#pragma unroll
          for (int i = 0; i + s < K; i += 2 * s) {
            bool take = cv[i + s] > cv[i];  // strict: earliest max wins (jnp.argmax)
            cv[i] = take ? cv[i + s] : cv[i];
            ci[i] = take ? ci[i + s] : ci[i];
          }
        }
        if (act) {
          hist_s[(t - 1) * K + j] = (unsigned char)ci[0];
          score = cv[0] + em_s[t * K + j];
        }
      } else if (act) {
        hist_s[(t - 1) * K + j] = (unsigned char)j;
      }
    }
    if (act) sc_s[j] = score + endv[j];
    __syncthreads();
    if (j == 0) {
      float best = -3.0e38f;
      int cur = 0;
#pragma unroll
      for (int i = 0; i < K; i++)
        if (sc_s[i] > best) { best = sc_s[i]; cur = i; }
      outdec[b * T + (T - 1)] = (float)cur;
      for (int t = T - 1; t >= 1; t--) {
        cur = hist_s[(t - 1) * K + cur];
        outdec[b * T + (t - 1)] = (float)cur;
      }
    }
  }
}

__global__ void nll_final_kernel(const float* __restrict__ parts,
                                 float* __restrict__ out) {
  out[0] = -0.25f * (parts[0] + parts[1] + parts[2] + parts[3]);
}

// ---------------- host launcher ----------------
extern "C" void kernel_launch(void* const* d_in, const int* in_sizes, int n_in,
                              void* d_out, int out_size, void* d_ws, size_t ws_size,
                              hipStream_t stream) {
  (void)in_sizes; (void)n_in; (void)out_size; (void)ws_size;
  const int* ids    = (const int*)d_in[0];
  const int* amask  = (const int*)d_in[1];
  const int* labels = (const int*)d_in[3];
  const float* wemb = (const float*)d_in[4];
  const float* pemb = (const float*)d_in[5];
  const float* temb = (const float*)d_in[6];
  const float* eg   = (const float*)d_in[7];
  const float* ebta = (const float*)d_in[8];
  const float* Wqkv = (const float*)d_in[9];
  const float* bqkv = (const float*)d_in[10];
  const float* Wo   = (const float*)d_in[11];
  const float* bo   = (const float*)d_in[12];
  const float* ln1g = (const float*)d_in[13];
  const float* ln1b = (const float*)d_in[14];
  const float* W1   = (const float*)d_in[15];
  const float* b1   = (const float*)d_in[16];
  const float* W2   = (const float*)d_in[17];
  const float* b2   = (const float*)d_in[18];
  const float* ln2g = (const float*)d_in[19];
  const float* ln2b = (const float*)d_in[20];
  const float* Wc   = (const float*)d_in[21];
  const float* bc   = (const float*)d_in[22];
  const float* cst  = (const float*)d_in[23];
  const float* cen  = (const float*)d_in[24];
  const float* ctr  = (const float*)d_in[25];
  float* out = (float*)d_out;

  // workspace layout (float units)
  float* ws = (float*)d_ws;
  float* h    = ws;                                  // 1,572,864
  unsigned short* hh = (unsigned short*)(h + 1572864);      //   786,432 f
  unsigned short* hl = (unsigned short*)(h + 1572864 + 786432);
  float* qkv  = h + 1572864 + 786432 * 2;            // 4,718,592
  unsigned short* cth = (unsigned short*)(qkv + 4718592);   //   786,432 f
  unsigned short* ctl = (unsigned short*)(qkv + 4718592 + 786432);
  float* tmp  = qkv + 4718592 + 786432 * 2;          // 1,572,864
  float* big  = tmp + 1572864;                       // 12,582,912 (scores / ffn1)
  unsigned short* gh = (unsigned short*)(big + 12582912);   // 3,145,728 f
  unsigned short* gl = (unsigned short*)(big + 12582912 + 3145728);
  unsigned short* Wth = (unsigned short*)(big + 12582912 + 3145728 * 2);  // 3,538,944 f
  unsigned short* Wtl = (unsigned short*)(big + 12582912 + 3145728 * 2 + 3538944);
  float* em   = big + 12582912 + 3145728 * 2 + 3538944 * 2; // 43,008
  float* parts = em + 43008;

  embed_ln_kernel<<<BT, 256, 0, stream>>>(ids, wemb, pemb, temb, eg, ebta, h, hh, hl);

  for (int l = 0; l < NLAYER; l++) {
    const float* wqkv_l = Wqkv + (size_t)l * H * 3 * H;
    const float* bqkv_l = bqkv + (size_t)l * 3 * H;
    const float* wo_l   = Wo + (size_t)l * H * H;
    const float* bo_l   = bo + (size_t)l * H;
    const float* w1_l   = W1 + (size_t)l * H * 4 * H;
    const float* b1_l   = b1 + (size_t)l * 4 * H;
    const float* w2_l   = W2 + (size_t)l * 4 * H * H;
    const float* b2_l   = b2 + (size_t)l * H;

    wconv_kernel<<<6912, 256, 0, stream>>>(wqkv_l, wo_l, w1_l, w2_l, Wth, Wtl);

    gemm_bf3_kernel<false><<<dim3(18, 16), 256, 0, stream>>>(
        hh, hl, Wth, Wtl, bqkv_l, qkv, 3 * H, H);
    qk_kernel<<<dim3(T / 64, T / 64, B * NH), 256, 0, stream>>>(qkv, amask, big);
    softmax_kernel<<<B * NH * T, 128, 0, stream>>>(big);
    pv_kernel<<<dim3(T / 64, B * NH), 256, 0, stream>>>(big, qkv, cth, ctl);
    gemm_bf3_kernel<false><<<dim3(6, 16), 256, 0, stream>>>(
        cth, ctl, Wth + 1769472, Wtl + 1769472, bo_l, tmp, H, H);
    add_ln_kernel<<<BT, 256, 0, stream>>>(h, tmp, ln1g + (size_t)l * H, ln1b + (size_t)l * H, hh, hl);
    gemm_bf3_kernel<true><<<dim3(24, 16), 256, 0, stream>>>(
        hh, hl, Wth + 2359296, Wtl + 2359296, b1_l, big, 4 * H, H);
    fsplit_kernel<<<6144, 256, 0, stream>>>(big, gh, gl, 2048 * 3072 / 4);
    gemm_bf3_kernel<false><<<dim3(6, 16), 256, 0, stream>>>(
        gh, gl, Wth + 4718592, Wtl + 4718592, b2_l, tmp, H, 4 * H);
    add_ln_kernel<<<BT, 256, 0, stream>>>(h, tmp, ln2g + (size_t)l * H, ln2b + (size_t)l * H, hh, hl);
  }

  classifier_kernel<<<(BT * K + 255) / 256, 256, 0, stream>>>(h, Wc, bc, em);
  crf_fused_kernel<<<8, 64, 0, stream>>>(em, labels, amask, cst, cen, ctr, parts, out + 1);
  nll_final_kernel<<<1, 1, 0, stream>>>(parts, out);
}

// Round 4
// 3727.343 us; speedup vs baseline: 1.4058x; 1.4058x over previous
//
#include <hip/hip_runtime.h>
#include <math.h>

constexpr int NLAYER = 12;
constexpr int H = 768;
constexpr int NH = 12;
constexpr int DH = 64;
constexpr int T = 512;
constexpr int B = 4;
constexpr int K = 21;
constexpr int BT = B * T;
constexpr float NEGB = -10000.0f;
constexpr float LNEPS = 1e-12f;
constexpr float INV_SQRT_DH = 0.125f;

typedef __attribute__((ext_vector_type(8))) short bf16x8;
typedef __attribute__((ext_vector_type(4))) float f32x4;
typedef __attribute__((ext_vector_type(4))) unsigned short u16x4;

// ---------------- helpers ----------------
__device__ __forceinline__ float wave_sum_f(float v) {
#pragma unroll
  for (int off = 32; off > 0; off >>= 1) v += __shfl_xor(v, off);
  return v;
}
__device__ __forceinline__ int wave_sum_i(int v) {
#pragma unroll
  for (int off = 32; off > 0; off >>= 1) v += __shfl_xor(v, off);
  return v;
}
__device__ __forceinline__ float readlane_f(float v, int i) {
  return __uint_as_float(__builtin_amdgcn_readlane(__float_as_uint(v), i));
}
__device__ __forceinline__ unsigned short f32_bf16_rn(float x) {
  unsigned int u = __float_as_uint(x);
  u += 0x7fffu + ((u >> 16) & 1u);
  return (unsigned short)(u >> 16);
}
__device__ __forceinline__ void split_bf16(float x, unsigned short& h, unsigned short& l) {
  h = f32_bf16_rn(x);
  float hf = __uint_as_float((unsigned int)h << 16);
  l = f32_bf16_rn(x - hf);
}
__device__ __forceinline__ void block_reduce_sum2(float& s, float& q) {
  __shared__ float red[8];
  s = wave_sum_f(s);
  q = wave_sum_f(q);
  int lane = threadIdx.x & 63, wid = threadIdx.x >> 6;
  if (lane == 0) { red[wid] = s; red[4 + wid] = q; }
  __syncthreads();
  s = red[0] + red[1] + red[2] + red[3];
  q = red[4] + red[5] + red[6] + red[7];
}

// ---------------- embedding + LN (emits f32 h and split bf16) ----------------
__global__ __launch_bounds__(256) void embed_ln_kernel(
    const int* __restrict__ ids, const float* __restrict__ wemb,
    const float* __restrict__ pemb, const float* __restrict__ temb,
    const float* __restrict__ g, const float* __restrict__ bta,
    float* __restrict__ h, unsigned short* __restrict__ hh,
    unsigned short* __restrict__ hl) {
  int row = blockIdx.x;
  int t = row % T;
  int id = ids[row];
  const float* wp = wemb + (size_t)id * H;
  const float* pp = pemb + (size_t)t * H;
  float x[3];
  float s = 0.f, q = 0.f;
#pragma unroll
  for (int i = 0; i < 3; i++) {
    int c = threadIdx.x + i * 256;
    x[i] = wp[c] + pp[c] + temb[c];
    s += x[i];
    q += x[i] * x[i];
  }
  block_reduce_sum2(s, q);
  float mean = s * (1.0f / H);
  float var = q * (1.0f / H) - mean * mean;
  float inv = rsqrtf(var + LNEPS);
#pragma unroll
  for (int i = 0; i < 3; i++) {
    int c = threadIdx.x + i * 256;
    float y = (x[i] - mean) * inv * g[c] + bta[c];
    h[(size_t)row * H + c] = y;
    unsigned short yh, yl;
    split_bf16(y, yh, yl);
    hh[(size_t)row * H + c] = yh;
    hl[(size_t)row * H + c] = yl;
  }
}

// ---------------- residual add + LN ----------------
__global__ __launch_bounds__(256) void add_ln_kernel(
    float* __restrict__ h, const float* __restrict__ add,
    const float* __restrict__ g, const float* __restrict__ bta,
    unsigned short* __restrict__ hh, unsigned short* __restrict__ hl) {
  int row = blockIdx.x;
  size_t base = (size_t)row * H;
  float x[3];
  float s = 0.f, q = 0.f;
#pragma unroll
  for (int i = 0; i < 3; i++) {
    int c = threadIdx.x + i * 256;
    x[i] = h[base + c] + add[base + c];
    s += x[i];
    q += x[i] * x[i];
  }
  block_reduce_sum2(s, q);
  float mean = s * (1.0f / H);
  float var = q * (1.0f / H) - mean * mean;
  float inv = rsqrtf(var + LNEPS);
#pragma unroll
  for (int i = 0; i < 3; i++) {
    int c = threadIdx.x + i * 256;
    float y = (x[i] - mean) * inv * g[c] + bta[c];
    h[base + c] = y;
    unsigned short yh, yl;
    split_bf16(y, yh, yl);
    hh[base + c] = yh;
    hl[base + c] = yl;
  }
}

// ---------------- per-layer weight transpose + split ----------------
__global__ __launch_bounds__(256) void wconv_kernel(
    const float* __restrict__ w0, const float* __restrict__ w1,
    const float* __restrict__ w2, const float* __restrict__ w3,
    unsigned short* __restrict__ Wth, unsigned short* __restrict__ Wtl) {
  __shared__ float tile[32][33];
  int bid = blockIdx.x;
  const float* src;
  int Kd, N, tk, tn;
  size_t off;
  if (bid < 1728) {
    src = w0; Kd = 768; N = 2304; tk = bid / 72; tn = bid % 72; off = 0;
  } else if (bid < 2304) {
    int t2 = bid - 1728; src = w1; Kd = 768; N = 768; tk = t2 / 24; tn = t2 % 24;
    off = 1769472;
  } else if (bid < 4608) {
    int t2 = bid - 2304; src = w2; Kd = 768; N = 3072; tk = t2 / 96; tn = t2 % 96;
    off = 2359296;
  } else {
    int t2 = bid - 4608; src = w3; Kd = 3072; N = 768; tk = t2 / 24; tn = t2 % 24;
    off = 4718592;
  }
  int tid = threadIdx.x;
  int k0 = tk * 32, n0 = tn * 32;
  int r = tid >> 3, c = (tid & 7) * 4;
  float4 v = *(const float4*)(src + (size_t)(k0 + r) * N + n0 + c);
  tile[r][c + 0] = v.x; tile[r][c + 1] = v.y; tile[r][c + 2] = v.z; tile[r][c + 3] = v.w;
  __syncthreads();
  u16x4 hv, lv;
#pragma unroll
  for (int q2 = 0; q2 < 4; q2++) {
    unsigned short sh, sl;
    split_bf16(tile[c + q2][r], sh, sl);
    hv[q2] = sh; lv[q2] = sl;
  }
  size_t dst = off + (size_t)(n0 + r) * Kd + k0 + c;
  *(u16x4*)(Wth + dst) = hv;
  *(u16x4*)(Wtl + dst) = lv;
}

// ---------------- bf16 3-term MFMA GEMM (pre-split operands) ----------------
// C[M,N] = A @ W + bias ; A split (Ah,Al)[M][Kd] ; W^T split (Wth,Wtl)[N][Kd]
// BM=128, BN template (128 or 64), BK=32, 4 waves 2x2.
template <int BN, bool GELU, bool SPLITOUT>
__global__ __launch_bounds__(256) void gemm_bf3_kernel(
    const unsigned short* __restrict__ Ah, const unsigned short* __restrict__ Al,
    const unsigned short* __restrict__ Wth, const unsigned short* __restrict__ Wtl,
    const float* __restrict__ bias, float* __restrict__ C,
    unsigned short* __restrict__ Ch, unsigned short* __restrict__ Cl,
    int N, int Kd) {
  constexpr int WN = BN / 2;
  constexpr int FN = WN / 16;
  constexpr int AW = 128 * 32;   // shorts per A tile
  constexpr int WW = BN * 32;    // shorts per W tile
  __shared__ short lds_s[2 * AW + 2 * WW];
  int tid = threadIdx.x;
  int lane = tid & 63, wid = tid >> 6;
  int wr = wid >> 1, wc = wid & 1;
  int bm = blockIdx.y * 128, bn = blockIdx.x * BN;
  f32x4 acc[4][FN] = {};
  int lrow = lane >> 2, lslot = lane & 3;

  const unsigned short* sbase;
  int rowbase, ldsoff, nchunks;
  if (wid == 0)      { sbase = Ah;  rowbase = bm; ldsoff = 0;            nchunks = 8; }
  else if (wid == 1) { sbase = Al;  rowbase = bm; ldsoff = AW;           nchunks = 8; }
  else if (wid == 2) { sbase = Wth; rowbase = bn; ldsoff = 2 * AW;       nchunks = BN / 16; }
  else               { sbase = Wtl; rowbase = bn; ldsoff = 2 * AW + WW;  nchunks = BN / 16; }

  for (int k0 = 0; k0 < Kd; k0 += 32) {
#pragma unroll
    for (int c = 0; c < 8; c++) {
      if (c < nchunks) {
        const unsigned short* src =
            sbase + (size_t)(rowbase + c * 16 + lrow) * Kd + k0 + lslot * 8;
        char* dst = ((char*)lds_s) + ldsoff * 2 + c * 1024 + lane * 16;
        __builtin_amdgcn_global_load_lds(
            (const __attribute__((address_space(1))) void*)src,
            (__attribute__((address_space(3))) void*)dst, 16, 0, 0);
      }
    }
    __syncthreads();
    int lr = lane & 15, lg = lane >> 4;
    bf16x8 af_h[4], af_l[4], wf_h[FN], wf_l[FN];
#pragma unroll
    for (int i = 0; i < 4; i++) {
      int e = (wr * 64 + i * 16 + lr) * 32 + lg * 8;
      af_h[i] = *(const bf16x8*)&lds_s[e];
      af_l[i] = *(const bf16x8*)&lds_s[AW + e];
    }
#pragma unroll
    for (int j = 0; j < FN; j++) {
      int e = (wc * WN + j * 16 + lr) * 32 + lg * 8;
      wf_h[j] = *(const bf16x8*)&lds_s[2 * AW + e];
      wf_l[j] = *(const bf16x8*)&lds_s[2 * AW + WW + e];
    }
#pragma unroll
    for (int i = 0; i < 4; i++)
#pragma unroll
      for (int j = 0; j < FN; j++) {
        acc[i][j] = __builtin_amdgcn_mfma_f32_16x16x32_bf16(af_h[i], wf_h[j], acc[i][j], 0, 0, 0);
        acc[i][j] = __builtin_amdgcn_mfma_f32_16x16x32_bf16(af_l[i], wf_h[j], acc[i][j], 0, 0, 0);
        acc[i][j] = __builtin_amdgcn_mfma_f32_16x16x32_bf16(af_h[i], wf_l[j], acc[i][j], 0, 0, 0);
      }
    __syncthreads();
  }
  int lr = lane & 15, lg = lane >> 4;
#pragma unroll
  for (int i = 0; i < 4; i++) {
#pragma unroll
    for (int j = 0; j < FN; j++) {
      int row = bm + wr * 64 + i * 16 + lg * 4;
      int col = bn + wc * WN + j * 16 + lr;
      float bv = bias[col];
#pragma unroll
      for (int r = 0; r < 4; r++) {
        float v = acc[i][j][r] + bv;
        if (GELU) v = 0.5f * v * (1.0f + erff(v * 0.70710678118654752f));
        if (SPLITOUT) {
          unsigned short sh, sl;
          split_bf16(v, sh, sl);
          Ch[(size_t)(row + r) * N + col] = sh;
          Cl[(size_t)(row + r) * N + col] = sl;
        } else {
          C[(size_t)(row + r) * N + col] = v;
        }
      }
    }
  }
}

// ---------------- S = Q K^T * scale + mask bias ----------------
__global__ __launch_bounds__(256) void qk_kernel(
    const float* __restrict__ qkv, const int* __restrict__ mask,
    float* __restrict__ S) {
  int bh = blockIdx.z;
  int b = bh / NH, hh = bh % NH;
  int i0 = blockIdx.y * 64, j0 = blockIdx.x * 64;
  __shared__ float Qs[64][64];
  __shared__ float Ks[64][64];
  int tid = threadIdx.x;
  int r = tid >> 2;
  int cseg = (tid & 3) * 16;
  const float* qbase = qkv + (size_t)(b * T + i0 + r) * (3 * H) + hh * DH;
  const float* kbase = qkv + (size_t)(b * T + j0 + r) * (3 * H) + H + hh * DH;
#pragma unroll
  for (int ss = 0; ss < 4; ss++) {
    int c = cseg + ss * 4;
    float4 qa = *(const float4*)(qbase + c);
    float4 ka = *(const float4*)(kbase + c);
    Qs[c + 0][r] = qa.x; Qs[c + 1][r] = qa.y; Qs[c + 2][r] = qa.z; Qs[c + 3][r] = qa.w;
    Ks[c + 0][r] = ka.x; Ks[c + 1][r] = ka.y; Ks[c + 2][r] = ka.z; Ks[c + 3][r] = ka.w;
  }
  __syncthreads();
  int tx = tid & 15, ty = tid >> 4;
  float acc[4][4] = {};
#pragma unroll 4
  for (int d = 0; d < 64; d++) {
    float a_[4], b_[4];
    *(float4*)a_ = *(const float4*)&Qs[d][ty * 4];
    *(float4*)b_ = *(const float4*)&Ks[d][tx * 4];
#pragma unroll
    for (int i = 0; i < 4; i++)
#pragma unroll
      for (int j = 0; j < 4; j++)
        acc[i][j] = fmaf(a_[i], b_[j], acc[i][j]);
  }
  float bj[4];
#pragma unroll
  for (int q = 0; q < 4; q++)
    bj[q] = (1.0f - (float)mask[b * T + j0 + tx * 4 + q]) * NEGB;
#pragma unroll
  for (int i = 0; i < 4; i++) {
    int gi = i0 + ty * 4 + i;
    int gj = j0 + tx * 4;
    float4 o;
    o.x = acc[i][0] * INV_SQRT_DH + bj[0];
    o.y = acc[i][1] * INV_SQRT_DH + bj[1];
    o.z = acc[i][2] * INV_SQRT_DH + bj[2];
    o.w = acc[i][3] * INV_SQRT_DH + bj[3];
    *(float4*)(S + ((size_t)bh * T + gi) * T + gj) = o;
  }
}

// ---------------- row softmax ----------------
__global__ __launch_bounds__(128) void softmax_kernel(float* __restrict__ S) {
  size_t row = blockIdx.x;
  float* p = S + row * T;
  int tid = threadIdx.x;
  float4 v = *(float4*)(p + tid * 4);
  float m = fmaxf(fmaxf(v.x, v.y), fmaxf(v.z, v.w));
#pragma unroll
  for (int off = 32; off > 0; off >>= 1) m = fmaxf(m, __shfl_xor(m, off));
  __shared__ float redm[2];
  __shared__ float reds[2];
  int wid = tid >> 6;
  if ((tid & 63) == 0) redm[wid] = m;
  __syncthreads();
  m = fmaxf(redm[0], redm[1]);
  v.x = __expf(v.x - m);
  v.y = __expf(v.y - m);
  v.z = __expf(v.z - m);
  v.w = __expf(v.w - m);
  float s = v.x + v.y + v.z + v.w;
  s = wave_sum_f(s);
  if ((tid & 63) == 0) reds[wid] = s;
  __syncthreads();
  s = reds[0] + reds[1];
  float inv = 1.0f / s;
  v.x *= inv; v.y *= inv; v.z *= inv; v.w *= inv;
  *(float4*)(p + tid * 4) = v;
}

// ---------------- ctx = P * V (emits split bf16 ctx) ----------------
__global__ __launch_bounds__(256) void pv_kernel(
    const float* __restrict__ S, const float* __restrict__ qkv,
    unsigned short* __restrict__ cth, unsigned short* __restrict__ ctl) {
  int bh = blockIdx.y;
  int b = bh / NH, hh = bh % NH;
  int i0 = blockIdx.x * 64;
  __shared__ float Ps[64][68];
  __shared__ float Vs[64][64];
  int tid = threadIdx.x;
  int r = tid >> 2;
  int cseg = (tid & 3) * 16;
  int tx = tid & 15, ty = tid >> 4;
  float acc[4][4] = {};
  const float* srow = S + ((size_t)bh * T + i0 + r) * T;
  const float* vbase = qkv + (size_t)(b * T) * (3 * H) + 2 * H + hh * DH;
  for (int k0 = 0; k0 < T; k0 += 64) {
    __syncthreads();
#pragma unroll
    for (int ss = 0; ss < 4; ss++) {
      int c = cseg + ss * 4;
      *(float4*)&Ps[r][c] = *(const float4*)(srow + k0 + c);
      *(float4*)&Vs[r][c] = *(const float4*)(vbase + (size_t)(k0 + r) * (3 * H) + c);
    }
    __syncthreads();
#pragma unroll
    for (int kk = 0; kk < 64; kk += 4) {
      float p_[4][4], v_[4][4];
#pragma unroll
      for (int i = 0; i < 4; i++)
        *(float4*)p_[i] = *(const float4*)&Ps[ty * 4 + i][kk];
#pragma unroll
      for (int s = 0; s < 4; s++)
        *(float4*)v_[s] = *(const float4*)&Vs[kk + s][tx * 4];
#pragma unroll
      for (int i = 0; i < 4; i++)
#pragma unroll
        for (int s = 0; s < 4; s++)
#pragma unroll
          for (int j = 0; j < 4; j++)
            acc[i][j] = fmaf(p_[i][s], v_[s][j], acc[i][j]);
    }
  }
#pragma unroll
  for (int i = 0; i < 4; i++) {
    int gi = i0 + ty * 4 + i;
    size_t idx = (size_t)(b * T + gi) * H + hh * DH + tx * 4;
    u16x4 hv, lv;
#pragma unroll
    for (int j = 0; j < 4; j++) {
      unsigned short sh, sl;
      split_bf16(acc[i][j], sh, sl);
      hv[j] = sh; lv[j] = sl;
    }
    *(u16x4*)(cth + idx) = hv;
    *(u16x4*)(ctl + idx) = lv;
  }
}

// ---------------- classifier ----------------
__global__ __launch_bounds__(256) void classifier_kernel(
    const float* __restrict__ h, const float* __restrict__ Wc,
    const float* __restrict__ bc, float* __restrict__ em) {
  int id = blockIdx.x * 256 + threadIdx.x;
  if (id >= BT * K) return;
  int row = id / K, k = id % K;
  float acc = bc[k];
  const float* hr = h + (size_t)row * H;
  for (int d = 0; d < H; d++) acc = fmaf(hr[d], Wc[d * K + k], acc);
  em[id] = acc;
}

// first-max merge (strict >, left/earlier index wins ties == jnp.argmax)
#define MRG(vo, io, va, ia, vb, ib) \
  float vo = ((vb) > (va)) ? (vb) : (va); \
  int io = ((vb) > (va)) ? (ib) : (ia);

// ---------------- fused CRF nll + viterbi ----------------
__global__ __launch_bounds__(64) void crf_fused_kernel(
    const float* __restrict__ em, const int* __restrict__ labels,
    const int* __restrict__ mask, const float* __restrict__ start,
    const float* __restrict__ endv, const float* __restrict__ trans,
    float* __restrict__ parts, float* __restrict__ outdec) {
  __shared__ float em_s[T * K];
  __shared__ int mask_s[T];
  __shared__ unsigned char hist_s[(T - 1) * K];
  __shared__ float sc_s[32];
  __shared__ __align__(16) float bcast[24];
  int b = blockIdx.x & 3;
  int role = blockIdx.x >> 2;
  int j = threadIdx.x;
  const float* eb = em + (size_t)b * T * K;
  for (int i = j; i < T * K / 4; i += 64)
    ((float4*)em_s)[i] = ((const float4*)eb)[i];
  for (int i = j; i < T; i += 64) mask_s[i] = mask[b * T + i];
  __syncthreads();
  bool act = (j < K);
  float tr[K];
#pragma unroll
  for (int i = 0; i < K; i++) tr[i] = act ? trans[i * K + j] : 0.f;

  if (role == 0) {
    // ---- numerator ----
    const int* tb = labels + b * T;
    float numloc = 0.f;
    int cnt = 0;
    for (int t = j; t < T; t += 64) {
      cnt += mask_s[t];
      if (t >= 1 && mask_s[t]) {
        int tp = tb[t - 1], tc = tb[t];
        numloc += trans[tp * K + tc] + em_s[t * K + tc];
      }
    }
    float num = wave_sum_f(numloc);
    int cnttot = wave_sum_i(cnt);
    // ---- forward recursion: exp-factorized, LDS-broadcast, named-var dot ----
    float etr[K];
#pragma unroll
    for (int i = 0; i < K; i++) etr[i] = __expf(tr[i]);
    float alpha = act ? (start[j] + em_s[j]) : 0.f;
    for (int t = 1; t < T; t++) {
      if (!mask_s[t]) continue;
      float m0 = readlane_f(alpha, 0);
      float ee = __expf(alpha - m0);
      if (act) bcast[j] = ee;
      __syncthreads();
      float4 B0 = *(const float4*)&bcast[0];
      float4 B1 = *(const float4*)&bcast[4];
      float4 B2 = *(const float4*)&bcast[8];
      float4 B3 = *(const float4*)&bcast[12];
      float4 B4 = *(const float4*)&bcast[16];
      float B20 = bcast[20];
      float a0 = fmaf(B4.x, etr[16], fmaf(B3.x, etr[12], fmaf(B2.x, etr[8], fmaf(B1.x, etr[4], B0.x * etr[0]))));
      float a1 = fmaf(B4.y, etr[17], fmaf(B3.y, etr[13], fmaf(B2.y, etr[9], fmaf(B1.y, etr[5], B0.y * etr[1]))));
      float a2 = fmaf(B4.z, etr[18], fmaf(B3.z, etr[14], fmaf(B2.z, etr[10], fmaf(B1.z, etr[6], B0.z * etr[2]))));
      float a3 = fmaf(B4.w, etr[19], fmaf(B3.w, etr[15], fmaf(B2.w, etr[11], fmaf(B1.w, etr[7], B0.w * etr[3]))));
      float ssum = fmaf(B20, etr[20], (a0 + a1) + (a2 + a3));
      float nxt = __logf(ssum) + m0 + (act ? em_s[t * K + j] : 0.f);
      if (act) alpha = nxt;
      __syncthreads();
    }
    float aj = act ? (alpha + endv[j]) : -3.0e38f;
    float mm = aj;
#pragma unroll
    for (int off = 32; off > 0; off >>= 1) mm = fmaxf(mm, __shfl_xor(mm, off));
    float e2 = act ? __expf(aj - mm) : 0.f;
    float s2 = wave_sum_f(e2);
    float den = __logf(s2) + mm;
    if (j == 0) {
      int tag0 = tb[0];
      int lastidx = cnttot - 1;
      float numtot = num + start[tag0] + em_s[tag0] + endv[tb[lastidx]];
      parts[b] = numtot - den;
    }
  } else {
    // ---- Viterbi: LDS broadcast + explicit first-max tree ----
    float score = act ? (start[j] + em_s[j]) : 0.f;
    for (int t = 1; t < T; t++) {
      int mk = mask_s[t];
      if (mk) {
        if (act) bcast[j] = score;
        __syncthreads();
        float4 B0 = *(const float4*)&bcast[0];
        float4 B1 = *(const float4*)&bcast[4];
        float4 B2 = *(const float4*)&bcast[8];
        float4 B3 = *(const float4*)&bcast[12];
        float4 B4 = *(const float4*)&bcast[16];
        float B20 = bcast[20];
        float c0 = B0.x + tr[0],  c1 = B0.y + tr[1],  c2 = B0.z + tr[2],  c3 = B0.w + tr[3];
        float c4 = B1.x + tr[4],  c5 = B1.y + tr[5],  c6 = B1.z + tr[6],  c7 = B1.w + tr[7];
        float c8 = B2.x + tr[8],  c9 = B2.y + tr[9],  c10 = B2.z + tr[10], c11 = B2.w + tr[11];
        float c12 = B3.x + tr[12], c13 = B3.y + tr[13], c14 = B3.z + tr[14], c15 = B3.w + tr[15];
        float c16 = B4.x + tr[16], c17 = B4.y + tr[17], c18 = B4.z + tr[18], c19 = B4.w + tr[19];
        float c20 = B20 + tr[20];
        MRG(m0v, m0i, c0, 0, c1, 1)
        MRG(m1v, m1i, c2, 2, c3, 3)
        MRG(m2v, m2i, c4, 4, c5, 5)
        MRG(m3v, m3i, c6, 6, c7, 7)
        MRG(m4v, m4i, c8, 8, c9, 9)
        MRG(m5v, m5i, c10, 10, c11, 11)
        MRG(m6v, m6i, c12, 12, c13, 13)
        MRG(m7v, m7i, c14, 14, c15, 15)
        MRG(m8v, m8i, c16, 16, c17, 17)
        MRG(m9v, m9i, c18, 18, c19, 19)
        MRG(p0v, p0i, m0v, m0i, m1v, m1i)
        MRG(p1v, p1i, m2v, m2i, m3v, m3i)
        MRG(p2v, p2i, m4v, m4i, m5v, m5i)
        MRG(p3v, p3i, m6v, m6i, m7v, m7i)
        MRG(p4v, p4i, m8v, m8i, m9v, m9i)
        MRG(r0v, r0i, p0v, p0i, p1v, p1i)
        MRG(r1v, r1i, p2v, p2i, p3v, p3i)
        MRG(r2v, r2i, p4v, p4i, c20, 20)
        MRG(s0v, s0i, r0v, r0i, r1v, r1i)
        MRG(fv, fi, s0v, s0i, r2v, r2i)
        if (act) {
          hist_s[(t - 1) * K + j] = (unsigned char)fi;
          score = fv + em_s[t * K + j];
        }
        __syncthreads();
      } else if (act) {
        hist_s[(t - 1) * K + j] = (unsigned char)j;
      }
    }
    if (act) sc_s[j] = score + endv[j];
    __syncthreads();
    if (j == 0) {
      float best = -3.0e38f;
      int cur = 0;
#pragma unroll
      for (int i = 0; i < K; i++)
        if (sc_s[i] > best) { best = sc_s[i]; cur = i; }
      outdec[b * T + (T - 1)] = (float)cur;
      for (int t = T - 1; t >= 1; t--) {
        cur = hist_s[(t - 1) * K + cur];
        outdec[b * T + (t - 1)] = (float)cur;
      }
    }
  }
}

__global__ void nll_final_kernel(const float* __restrict__ parts,
                                 float* __restrict__ out) {
  out[0] = -0.25f * (parts[0] + parts[1] + parts[2] + parts[3]);
}

// ---------------- host launcher ----------------
extern "C" void kernel_launch(void* const* d_in, const int* in_sizes, int n_in,
                              void* d_out, int out_size, void* d_ws, size_t ws_size,
                              hipStream_t stream) {
  (void)in_sizes; (void)n_in; (void)out_size; (void)ws_size;
  const int* ids    = (const int*)d_in[0];
  const int* amask  = (const int*)d_in[1];
  const int* labels = (const int*)d_in[3];
  const float* wemb = (const float*)d_in[4];
  const float* pemb = (const float*)d_in[5];
  const float* temb = (const float*)d_in[6];
  const float* eg   = (const float*)d_in[7];
  const float* ebta = (const float*)d_in[8];
  const float* Wqkv = (const float*)d_in[9];
  const float* bqkv = (const float*)d_in[10];
  const float* Wo   = (const float*)d_in[11];
  const float* bo   = (const float*)d_in[12];
  const float* ln1g = (const float*)d_in[13];
  const float* ln1b = (const float*)d_in[14];
  const float* W1   = (const float*)d_in[15];
  const float* b1   = (const float*)d_in[16];
  const float* W2   = (const float*)d_in[17];
  const float* b2   = (const float*)d_in[18];
  const float* ln2g = (const float*)d_in[19];
  const float* ln2b = (const float*)d_in[20];
  const float* Wc   = (const float*)d_in[21];
  const float* bc   = (const float*)d_in[22];
  const float* cst  = (const float*)d_in[23];
  const float* cen  = (const float*)d_in[24];
  const float* ctr  = (const float*)d_in[25];
  float* out = (float*)d_out;

  // workspace layout (float units)
  float* ws = (float*)d_ws;
  float* h    = ws;                                       // 1,572,864
  unsigned short* hh = (unsigned short*)(h + 1572864);
  unsigned short* hl = (unsigned short*)(h + 1572864 + 786432);
  float* qkv  = h + 1572864 + 786432 * 2;                 // 4,718,592
  unsigned short* cth = (unsigned short*)(qkv + 4718592);
  unsigned short* ctl = (unsigned short*)(qkv + 4718592 + 786432);
  float* tmp  = qkv + 4718592 + 786432 * 2;               // 1,572,864
  float* big  = tmp + 1572864;                            // 12,582,912 (scores)
  unsigned short* gh = (unsigned short*)(big + 12582912); // 2048*3072 u16
  unsigned short* gl = (unsigned short*)(big + 12582912 + 3145728);
  unsigned short* Wth = (unsigned short*)(big + 12582912 + 3145728 * 2);
  unsigned short* Wtl = (unsigned short*)(big + 12582912 + 3145728 * 2 + 3538944);
  float* em   = big + 12582912 + 3145728 * 2 + 3538944 * 2;
  float* parts = em + 43008;

  embed_ln_kernel<<<BT, 256, 0, stream>>>(ids, wemb, pemb, temb, eg, ebta, h, hh, hl);

  for (int l = 0; l < NLAYER; l++) {
    const float* bqkv_l = bqkv + (size_t)l * 3 * H;
    const float* bo_l   = bo + (size_t)l * H;
    const float* b1_l   = b1 + (size_t)l * 4 * H;
    const float* b2_l   = b2 + (size_t)l * H;

    wconv_kernel<<<6912, 256, 0, stream>>>(
        Wqkv + (size_t)l * H * 3 * H, Wo + (size_t)l * H * H,
        W1 + (size_t)l * H * 4 * H, W2 + (size_t)l * 4 * H * H, Wth, Wtl);

    gemm_bf3_kernel<128, false, false><<<dim3(18, 16), 256, 0, stream>>>(
        hh, hl, Wth, Wtl, bqkv_l, qkv, nullptr, nullptr, 3 * H, H);
    qk_kernel<<<dim3(T / 64, T / 64, B * NH), 256, 0, stream>>>(qkv, amask, big);
    softmax_kernel<<<B * NH * T, 128, 0, stream>>>(big);
    pv_kernel<<<dim3(T / 64, B * NH), 256, 0, stream>>>(big, qkv, cth, ctl);
    gemm_bf3_kernel<64, false, false><<<dim3(12, 16), 256, 0, stream>>>(
        cth, ctl, Wth + 1769472, Wtl + 1769472, bo_l, tmp, nullptr, nullptr, H, H);
    add_ln_kernel<<<BT, 256, 0, stream>>>(h, tmp, ln1g + (size_t)l * H, ln1b + (size_t)l * H, hh, hl);
    gemm_bf3_kernel<128, true, true><<<dim3(24, 16), 256, 0, stream>>>(
        hh, hl, Wth + 2359296, Wtl + 2359296, b1_l, nullptr, gh, gl, 4 * H, H);
    gemm_bf3_kernel<64, false, false><<<dim3(12, 16), 256, 0, stream>>>(
        gh, gl, Wth + 4718592, Wtl + 4718592, b2_l, tmp, nullptr, nullptr, H, 4 * H);
    add_ln_kernel<<<BT, 256, 0, stream>>>(h, tmp, ln2g + (size_t)l * H, ln2b + (size_t)l * H, hh, hl);
  }

  classifier_kernel<<<(BT * K + 255) / 256, 256, 0, stream>>>(h, Wc, bc, em);
  crf_fused_kernel<<<8, 64, 0, stream>>>(em, labels, amask, cst, cen, ctr, parts, out + 1);
  nll_final_kernel<<<1, 1, 0, stream>>>(parts, out);
}

// Round 5
// 3354.457 us; speedup vs baseline: 1.5620x; 1.1112x over previous
//
#include <hip/hip_runtime.h>
#include <math.h>

constexpr int NLAYER = 12;
constexpr int H = 768;
constexpr int NH = 12;
constexpr int DH = 64;
constexpr int T = 512;
constexpr int B = 4;
constexpr int K = 21;
constexpr int BT = B * T;
constexpr float NEGB = -10000.0f;
constexpr float LNEPS = 1e-12f;
constexpr float INV_SQRT_DH = 0.125f;

typedef __attribute__((ext_vector_type(8))) short bf16x8;
typedef __attribute__((ext_vector_type(4))) float f32x4;
typedef __attribute__((ext_vector_type(4))) unsigned short u16x4;

#define WAIT_VMCNT(n) asm volatile("s_waitcnt vmcnt(" #n ")")

// ---------------- helpers ----------------
__device__ __forceinline__ float wave_sum_f(float v) {
#pragma unroll
  for (int off = 32; off > 0; off >>= 1) v += __shfl_xor(v, off);
  return v;
}
__device__ __forceinline__ int wave_sum_i(int v) {
#pragma unroll
  for (int off = 32; off > 0; off >>= 1) v += __shfl_xor(v, off);
  return v;
}
__device__ __forceinline__ float readlane_f(float v, int i) {
  return __uint_as_float(__builtin_amdgcn_readlane(__float_as_uint(v), i));
}
__device__ __forceinline__ unsigned short f32_bf16_rn(float x) {
  unsigned int u = __float_as_uint(x);
  u += 0x7fffu + ((u >> 16) & 1u);
  return (unsigned short)(u >> 16);
}
__device__ __forceinline__ void split_bf16(float x, unsigned short& h, unsigned short& l) {
  h = f32_bf16_rn(x);
  float hf = __uint_as_float((unsigned int)h << 16);
  l = f32_bf16_rn(x - hf);
}
__device__ __forceinline__ void block_reduce_sum2(float& s, float& q) {
  __shared__ float red[8];
  s = wave_sum_f(s);
  q = wave_sum_f(q);
  int lane = threadIdx.x & 63, wid = threadIdx.x >> 6;
  if (lane == 0) { red[wid] = s; red[4 + wid] = q; }
  __syncthreads();
  s = red[0] + red[1] + red[2] + red[3];
  q = red[4] + red[5] + red[6] + red[7];
}

// ---------------- embedding + LN (emits f32 h and split bf16) ----------------
__global__ __launch_bounds__(256) void embed_ln_kernel(
    const int* __restrict__ ids, const float* __restrict__ wemb,
    const float* __restrict__ pemb, const float* __restrict__ temb,
    const float* __restrict__ g, const float* __restrict__ bta,
    float* __restrict__ h, unsigned short* __restrict__ hh,
    unsigned short* __restrict__ hl) {
  int row = blockIdx.x;
  int t = row % T;
  int id = ids[row];
  const float* wp = wemb + (size_t)id * H;
  const float* pp = pemb + (size_t)t * H;
  float x[3];
  float s = 0.f, q = 0.f;
#pragma unroll
  for (int i = 0; i < 3; i++) {
    int c = threadIdx.x + i * 256;
    x[i] = wp[c] + pp[c] + temb[c];
    s += x[i];
    q += x[i] * x[i];
  }
  block_reduce_sum2(s, q);
  float mean = s * (1.0f / H);
  float var = q * (1.0f / H) - mean * mean;
  float inv = rsqrtf(var + LNEPS);
#pragma unroll
  for (int i = 0; i < 3; i++) {
    int c = threadIdx.x + i * 256;
    float y = (x[i] - mean) * inv * g[c] + bta[c];
    h[(size_t)row * H + c] = y;
    unsigned short yh, yl;
    split_bf16(y, yh, yl);
    hh[(size_t)row * H + c] = yh;
    hl[(size_t)row * H + c] = yl;
  }
}

// ---------------- residual add + LN ----------------
__global__ __launch_bounds__(256) void add_ln_kernel(
    float* __restrict__ h, const float* __restrict__ add,
    const float* __restrict__ g, const float* __restrict__ bta,
    unsigned short* __restrict__ hh, unsigned short* __restrict__ hl) {
  int row = blockIdx.x;
  size_t base = (size_t)row * H;
  float x[3];
  float s = 0.f, q = 0.f;
#pragma unroll
  for (int i = 0; i < 3; i++) {
    int c = threadIdx.x + i * 256;
    x[i] = h[base + c] + add[base + c];
    s += x[i];
    q += x[i] * x[i];
  }
  block_reduce_sum2(s, q);
  float mean = s * (1.0f / H);
  float var = q * (1.0f / H) - mean * mean;
  float inv = rsqrtf(var + LNEPS);
#pragma unroll
  for (int i = 0; i < 3; i++) {
    int c = threadIdx.x + i * 256;
    float y = (x[i] - mean) * inv * g[c] + bta[c];
    h[base + c] = y;
    unsigned short yh, yl;
    split_bf16(y, yh, yl);
    hh[base + c] = yh;
    hl[base + c] = yl;
  }
}

// ---------------- per-layer weight transpose + split ----------------
__global__ __launch_bounds__(256) void wconv_kernel(
    const float* __restrict__ w0, const float* __restrict__ w1,
    const float* __restrict__ w2, const float* __restrict__ w3,
    unsigned short* __restrict__ Wth, unsigned short* __restrict__ Wtl) {
  __shared__ float tile[32][33];
  int bid = blockIdx.x;
  const float* src;
  int Kd, N, tk, tn;
  size_t off;
  if (bid < 1728) {
    src = w0; Kd = 768; N = 2304; tk = bid / 72; tn = bid % 72; off = 0;
  } else if (bid < 2304) {
    int t2 = bid - 1728; src = w1; Kd = 768; N = 768; tk = t2 / 24; tn = t2 % 24;
    off = 1769472;
  } else if (bid < 4608) {
    int t2 = bid - 2304; src = w2; Kd = 768; N = 3072; tk = t2 / 96; tn = t2 % 96;
    off = 2359296;
  } else {
    int t2 = bid - 4608; src = w3; Kd = 3072; N = 768; tk = t2 / 24; tn = t2 % 24;
    off = 4718592;
  }
  int tid = threadIdx.x;
  int k0 = tk * 32, n0 = tn * 32;
  int r = tid >> 3, c = (tid & 7) * 4;
  float4 v = *(const float4*)(src + (size_t)(k0 + r) * N + n0 + c);
  tile[r][c + 0] = v.x; tile[r][c + 1] = v.y; tile[r][c + 2] = v.z; tile[r][c + 3] = v.w;
  __syncthreads();
  u16x4 hv, lv;
#pragma unroll
  for (int q2 = 0; q2 < 4; q2++) {
    unsigned short sh, sl;
    split_bf16(tile[c + q2][r], sh, sl);
    hv[q2] = sh; lv[q2] = sl;
  }
  size_t dst = off + (size_t)(n0 + r) * Kd + k0 + c;
  *(u16x4*)(Wth + dst) = hv;
  *(u16x4*)(Wtl + dst) = lv;
}

// ---------------- bf16 3-term MFMA GEMM, 2-phase double-buffered ----------------
// C[M,N] = A @ W + bias ; A split (Ah,Al)[M][Kd] ; W^T split (Wth,Wtl)[N][Kd]
// BM=128, BN template (128 or 64), BK=32, 4 waves 2x2, raw-barrier pipeline.
template <int BN, bool GELU, bool SPLITOUT>
__global__ __launch_bounds__(256) void gemm_bf3_kernel(
    const unsigned short* __restrict__ Ah, const unsigned short* __restrict__ Al,
    const unsigned short* __restrict__ Wth, const unsigned short* __restrict__ Wtl,
    const float* __restrict__ bias, float* __restrict__ C,
    unsigned short* __restrict__ Ch, unsigned short* __restrict__ Cl,
    int N, int Kd) {
  constexpr int WN = BN / 2;
  constexpr int FN = WN / 16;
  constexpr int AW = 128 * 32;          // shorts per A tile
  constexpr int WW = BN * 32;           // shorts per W tile
  constexpr int DBS = 2 * AW + 2 * WW;  // shorts per buffer
  __shared__ short lds_s[2 * DBS];
  int tid = threadIdx.x;
  int lane = tid & 63, wid = tid >> 6;
  int wr = wid >> 1, wc = wid & 1;
  int bm = blockIdx.y * 128, bn = blockIdx.x * BN;
  f32x4 acc[4][FN] = {};
  int lrow = lane >> 2, lslot = lane & 3;

  const unsigned short* sbase;
  int rowbase, ldsoff, nchunks;
  if (wid == 0)      { sbase = Ah;  rowbase = bm; ldsoff = 0;            nchunks = 8; }
  else if (wid == 1) { sbase = Al;  rowbase = bm; ldsoff = AW;           nchunks = 8; }
  else if (wid == 2) { sbase = Wth; rowbase = bn; ldsoff = 2 * AW;       nchunks = BN / 16; }
  else               { sbase = Wtl; rowbase = bn; ldsoff = 2 * AW + WW;  nchunks = BN / 16; }

  const unsigned short* srcbase = sbase + (size_t)(rowbase + lrow) * Kd + lslot * 8;

  auto STAGE = [&](int db, int k0) {
#pragma unroll
    for (int c = 0; c < 8; c++) {
      if (c < nchunks) {
        const unsigned short* src = srcbase + (size_t)(c * 16) * Kd + k0;
        char* dst = ((char*)lds_s) + (db * DBS + ldsoff) * 2 + c * 1024 + lane * 16;
        __builtin_amdgcn_global_load_lds(
            (const __attribute__((address_space(1))) void*)src,
            (__attribute__((address_space(3))) void*)dst, 16, 0, 0);
      }
    }
  };

  const int NT = Kd / 32;
  STAGE(0, 0);
  for (int kt = 0; kt < NT; kt++) {
    int cur = kt & 1;
    bool more = (kt + 1 < NT);
    if (more) STAGE(cur ^ 1, (kt + 1) * 32);
    // wait for current buffer's DMA (counted: next tile's loads stay in flight)
    if (more) {
      if (BN == 128 || wid < 2) { WAIT_VMCNT(8); } else { WAIT_VMCNT(4); }
    } else {
      WAIT_VMCNT(0);
    }
    __builtin_amdgcn_s_barrier();
    __builtin_amdgcn_sched_barrier(0);

    int lr = lane & 15, lg = lane >> 4;
    int cb = cur * DBS;
    bf16x8 af_h[4], af_l[4], wf_h[FN], wf_l[FN];
#pragma unroll
    for (int i = 0; i < 4; i++) {
      int e = (wr * 64 + i * 16 + lr) * 32 + lg * 8;
      af_h[i] = *(const bf16x8*)&lds_s[cb + e];
      af_l[i] = *(const bf16x8*)&lds_s[cb + AW + e];
    }
#pragma unroll
    for (int j = 0; j < FN; j++) {
      int e = (wc * WN + j * 16 + lr) * 32 + lg * 8;
      wf_h[j] = *(const bf16x8*)&lds_s[cb + 2 * AW + e];
      wf_l[j] = *(const bf16x8*)&lds_s[cb + 2 * AW + WW + e];
    }
#pragma unroll
    for (int i = 0; i < 4; i++)
#pragma unroll
      for (int j = 0; j < FN; j++) {
        acc[i][j] = __builtin_amdgcn_mfma_f32_16x16x32_bf16(af_h[i], wf_h[j], acc[i][j], 0, 0, 0);
        acc[i][j] = __builtin_amdgcn_mfma_f32_16x16x32_bf16(af_l[i], wf_h[j], acc[i][j], 0, 0, 0);
        acc[i][j] = __builtin_amdgcn_mfma_f32_16x16x32_bf16(af_h[i], wf_l[j], acc[i][j], 0, 0, 0);
      }
    asm volatile("s_waitcnt lgkmcnt(0)");
    __builtin_amdgcn_sched_barrier(0);
    __builtin_amdgcn_s_barrier();   // buf[cur] free for next iteration's STAGE
    __builtin_amdgcn_sched_barrier(0);
  }

  int lr = lane & 15, lg = lane >> 4;
#pragma unroll
  for (int i = 0; i < 4; i++) {
#pragma unroll
    for (int j = 0; j < FN; j++) {
      int row = bm + wr * 64 + i * 16 + lg * 4;
      int col = bn + wc * WN + j * 16 + lr;
      float bv = bias[col];
#pragma unroll
      for (int r = 0; r < 4; r++) {
        float v = acc[i][j][r] + bv;
        if (GELU) v = 0.5f * v * (1.0f + erff(v * 0.70710678118654752f));
        if (SPLITOUT) {
          unsigned short sh, sl;
          split_bf16(v, sh, sl);
          Ch[(size_t)(row + r) * N + col] = sh;
          Cl[(size_t)(row + r) * N + col] = sl;
        } else {
          C[(size_t)(row + r) * N + col] = v;
        }
      }
    }
  }
}

// ---------------- S = Q K^T * scale + mask bias ----------------
__global__ __launch_bounds__(256) void qk_kernel(
    const float* __restrict__ qkv, const int* __restrict__ mask,
    float* __restrict__ S) {
  int bh = blockIdx.z;
  int b = bh / NH, hh = bh % NH;
  int i0 = blockIdx.y * 64, j0 = blockIdx.x * 64;
  __shared__ float Qs[64][64];
  __shared__ float Ks[64][64];
  int tid = threadIdx.x;
  int r = tid >> 2;
  int cseg = (tid & 3) * 16;
  const float* qbase = qkv + (size_t)(b * T + i0 + r) * (3 * H) + hh * DH;
  const float* kbase = qkv + (size_t)(b * T + j0 + r) * (3 * H) + H + hh * DH;
#pragma unroll
  for (int ss = 0; ss < 4; ss++) {
    int c = cseg + ss * 4;
    float4 qa = *(const float4*)(qbase + c);
    float4 ka = *(const float4*)(kbase + c);
    Qs[c + 0][r] = qa.x; Qs[c + 1][r] = qa.y; Qs[c + 2][r] = qa.z; Qs[c + 3][r] = qa.w;
    Ks[c + 0][r] = ka.x; Ks[c + 1][r] = ka.y; Ks[c + 2][r] = ka.z; Ks[c + 3][r] = ka.w;
  }
  __syncthreads();
  int tx = tid & 15, ty = tid >> 4;
  float acc[4][4] = {};
#pragma unroll 4
  for (int d = 0; d < 64; d++) {
    float a_[4], b_[4];
    *(float4*)a_ = *(const float4*)&Qs[d][ty * 4];
    *(float4*)b_ = *(const float4*)&Ks[d][tx * 4];
#pragma unroll
    for (int i = 0; i < 4; i++)
#pragma unroll
      for (int j = 0; j < 4; j++)
        acc[i][j] = fmaf(a_[i], b_[j], acc[i][j]);
  }
  float bj[4];
#pragma unroll
  for (int q = 0; q < 4; q++)
    bj[q] = (1.0f - (float)mask[b * T + j0 + tx * 4 + q]) * NEGB;
#pragma unroll
  for (int i = 0; i < 4; i++) {
    int gi = i0 + ty * 4 + i;
    int gj = j0 + tx * 4;
    float4 o;
    o.x = acc[i][0] * INV_SQRT_DH + bj[0];
    o.y = acc[i][1] * INV_SQRT_DH + bj[1];
    o.z = acc[i][2] * INV_SQRT_DH + bj[2];
    o.w = acc[i][3] * INV_SQRT_DH + bj[3];
    *(float4*)(S + ((size_t)bh * T + gi) * T + gj) = o;
  }
}

// ---------------- row softmax ----------------
__global__ __launch_bounds__(128) void softmax_kernel(float* __restrict__ S) {
  size_t row = blockIdx.x;
  float* p = S + row * T;
  int tid = threadIdx.x;
  float4 v = *(float4*)(p + tid * 4);
  float m = fmaxf(fmaxf(v.x, v.y), fmaxf(v.z, v.w));
#pragma unroll
  for (int off = 32; off > 0; off >>= 1) m = fmaxf(m, __shfl_xor(m, off));
  __shared__ float redm[2];
  __shared__ float reds[2];
  int wid = tid >> 6;
  if ((tid & 63) == 0) redm[wid] = m;
  __syncthreads();
  m = fmaxf(redm[0], redm[1]);
  v.x = __expf(v.x - m);
  v.y = __expf(v.y - m);
  v.z = __expf(v.z - m);
  v.w = __expf(v.w - m);
  float s = v.x + v.y + v.z + v.w;
  s = wave_sum_f(s);
  if ((tid & 63) == 0) reds[wid] = s;
  __syncthreads();
  s = reds[0] + reds[1];
  float inv = 1.0f / s;
  v.x *= inv; v.y *= inv; v.z *= inv; v.w *= inv;
  *(float4*)(p + tid * 4) = v;
}

// ---------------- ctx = P * V (emits split bf16 ctx) ----------------
__global__ __launch_bounds__(256) void pv_kernel(
    const float* __restrict__ S, const float* __restrict__ qkv,
    unsigned short* __restrict__ cth, unsigned short* __restrict__ ctl) {
  int bh = blockIdx.y;
  int b = bh / NH, hh = bh % NH;
  int i0 = blockIdx.x * 64;
  __shared__ float Ps[64][68];
  __shared__ float Vs[64][64];
  int tid = threadIdx.x;
  int r = tid >> 2;
  int cseg = (tid & 3) * 16;
  int tx = tid & 15, ty = tid >> 4;
  float acc[4][4] = {};
  const float* srow = S + ((size_t)bh * T + i0 + r) * T;
  const float* vbase = qkv + (size_t)(b * T) * (3 * H) + 2 * H + hh * DH;
  for (int k0 = 0; k0 < T; k0 += 64) {
    __syncthreads();
#pragma unroll
    for (int ss = 0; ss < 4; ss++) {
      int c = cseg + ss * 4;
      *(float4*)&Ps[r][c] = *(const float4*)(srow + k0 + c);
      *(float4*)&Vs[r][c] = *(const float4*)(vbase + (size_t)(k0 + r) * (3 * H) + c);
    }
    __syncthreads();
#pragma unroll
    for (int kk = 0; kk < 64; kk += 4) {
      float p_[4][4], v_[4][4];
#pragma unroll
      for (int i = 0; i < 4; i++)
        *(float4*)p_[i] = *(const float4*)&Ps[ty * 4 + i][kk];
#pragma unroll
      for (int s = 0; s < 4; s++)
        *(float4*)v_[s] = *(const float4*)&Vs[kk + s][tx * 4];
#pragma unroll
      for (int i = 0; i < 4; i++)
#pragma unroll
        for (int s = 0; s < 4; s++)
#pragma unroll
          for (int j = 0; j < 4; j++)
            acc[i][j] = fmaf(p_[i][s], v_[s][j], acc[i][j]);
    }
  }
#pragma unroll
  for (int i = 0; i < 4; i++) {
    int gi = i0 + ty * 4 + i;
    size_t idx = (size_t)(b * T + gi) * H + hh * DH + tx * 4;
    u16x4 hv, lv;
#pragma unroll
    for (int j = 0; j < 4; j++) {
      unsigned short sh, sl;
      split_bf16(acc[i][j], sh, sl);
      hv[j] = sh; lv[j] = sl;
    }
    *(u16x4*)(cth + idx) = hv;
    *(u16x4*)(ctl + idx) = lv;
  }
}

// ---------------- classifier ----------------
__global__ __launch_bounds__(256) void classifier_kernel(
    const float* __restrict__ h, const float* __restrict__ Wc,
    const float* __restrict__ bc, float* __restrict__ em) {
  int id = blockIdx.x * 256 + threadIdx.x;
  if (id >= BT * K) return;
  int row = id / K, k = id % K;
  float acc = bc[k];
  const float* hr = h + (size_t)row * H;
  for (int d = 0; d < H; d++) acc = fmaf(hr[d], Wc[d * K + k], acc);
  em[id] = acc;
}

// first-max merge (strict >, left/earlier index wins ties == jnp.argmax)
#define MRG(vo, io, va, ia, vb, ib) \
  float vo = ((vb) > (va)) ? (vb) : (va); \
  int io = ((vb) > (va)) ? (ib) : (ia);

// ---------------- fused CRF nll + viterbi (readlane broadcast) ----------------
__global__ __launch_bounds__(64) void crf_fused_kernel(
    const float* __restrict__ em, const int* __restrict__ labels,
    const int* __restrict__ mask, const float* __restrict__ start,
    const float* __restrict__ endv, const float* __restrict__ trans,
    float* __restrict__ parts, float* __restrict__ outdec) {
  __shared__ float em_s[T * K];
  __shared__ int mask_s[T];
  __shared__ unsigned char hist_s[(T - 1) * K];
  __shared__ float sc_s[32];
  int b = blockIdx.x & 3;
  int role = blockIdx.x >> 2;
  int j = threadIdx.x;
  const float* eb = em + (size_t)b * T * K;
  for (int i = j; i < T * K / 4; i += 64)
    ((float4*)em_s)[i] = ((const float4*)eb)[i];
  for (int i = j; i < T; i += 64) mask_s[i] = mask[b * T + i];
  __syncthreads();
  bool act = (j < K);
  float tr[K];
#pragma unroll
  for (int i = 0; i < K; i++) tr[i] = act ? trans[i * K + j] : 0.f;

  if (role == 0) {
    // ---- numerator ----
    const int* tb = labels + b * T;
    float numloc = 0.f;
    int cnt = 0;
    for (int t = j; t < T; t += 64) {
      cnt += mask_s[t];
      if (t >= 1 && mask_s[t]) {
        int tp = tb[t - 1], tc = tb[t];
        numloc += trans[tp * K + tc] + em_s[t * K + tc];
      }
    }
    float num = wave_sum_f(numloc);
    int cnttot = wave_sum_i(cnt);
    // ---- forward recursion: exp-factorized, readlane broadcast ----
    float etr[K];
#pragma unroll
    for (int i = 0; i < K; i++) etr[i] = __expf(tr[i]);
    float alpha = act ? (start[j] + em_s[j]) : 0.f;
    for (int t = 1; t < T; t++) {
      if (!mask_s[t]) continue;
      float m0 = readlane_f(alpha, 0);
      float ee = __expf(alpha - m0);
      float e0 = readlane_f(ee, 0),  e1 = readlane_f(ee, 1),  e2 = readlane_f(ee, 2);
      float e3 = readlane_f(ee, 3),  e4 = readlane_f(ee, 4),  e5 = readlane_f(ee, 5);
      float e6 = readlane_f(ee, 6),  e7 = readlane_f(ee, 7),  e8 = readlane_f(ee, 8);
      float e9 = readlane_f(ee, 9),  e10 = readlane_f(ee, 10), e11 = readlane_f(ee, 11);
      float e12 = readlane_f(ee, 12), e13 = readlane_f(ee, 13), e14 = readlane_f(ee, 14);
      float e15 = readlane_f(ee, 15), e16 = readlane_f(ee, 16), e17 = readlane_f(ee, 17);
      float e18 = readlane_f(ee, 18), e19 = readlane_f(ee, 19), e20 = readlane_f(ee, 20);
      float a0 = fmaf(e16, etr[16], fmaf(e12, etr[12], fmaf(e8, etr[8],  fmaf(e4, etr[4], e0 * etr[0]))));
      float a1 = fmaf(e17, etr[17], fmaf(e13, etr[13], fmaf(e9, etr[9],  fmaf(e5, etr[5], e1 * etr[1]))));
      float a2 = fmaf(e18, etr[18], fmaf(e14, etr[14], fmaf(e10, etr[10], fmaf(e6, etr[6], e2 * etr[2]))));
      float a3 = fmaf(e19, etr[19], fmaf(e15, etr[15], fmaf(e11, etr[11], fmaf(e7, etr[7], e3 * etr[3]))));
      float ssum = fmaf(e20, etr[20], (a0 + a1) + (a2 + a3));
      float nxt = __logf(ssum) + m0 + (act ? em_s[t * K + j] : 0.f);
      if (act) alpha = nxt;
    }
    float aj = act ? (alpha + endv[j]) : -3.0e38f;
    float mm = aj;
#pragma unroll
    for (int off = 32; off > 0; off >>= 1) mm = fmaxf(mm, __shfl_xor(mm, off));
    float e2v = act ? __expf(aj - mm) : 0.f;
    float s2 = wave_sum_f(e2v);
    float den = __logf(s2) + mm;
    if (j == 0) {
      int tag0 = tb[0];
      int lastidx = cnttot - 1;
      float numtot = num + start[tag0] + em_s[tag0] + endv[tb[lastidx]];
      parts[b] = numtot - den;
    }
  } else {
    // ---- Viterbi: readlane broadcast + explicit first-max tree ----
    float score = act ? (start[j] + em_s[j]) : 0.f;
    for (int t = 1; t < T; t++) {
      int mk = mask_s[t];
      if (mk) {
        float c0 = readlane_f(score, 0) + tr[0],   c1 = readlane_f(score, 1) + tr[1];
        float c2 = readlane_f(score, 2) + tr[2],   c3 = readlane_f(score, 3) + tr[3];
        float c4 = readlane_f(score, 4) + tr[4],   c5 = readlane_f(score, 5) + tr[5];
        float c6 = readlane_f(score, 6) + tr[6],   c7 = readlane_f(score, 7) + tr[7];
        float c8 = readlane_f(score, 8) + tr[8],   c9 = readlane_f(score, 9) + tr[9];
        float c10 = readlane_f(score, 10) + tr[10], c11 = readlane_f(score, 11) + tr[11];
        float c12 = readlane_f(score, 12) + tr[12], c13 = readlane_f(score, 13) + tr[13];
        float c14 = readlane_f(score, 14) + tr[14], c15 = readlane_f(score, 15) + tr[15];
        float c16 = readlane_f(score, 16) + tr[16], c17 = readlane_f(score, 17) + tr[17];
        float c18 = readlane_f(score, 18) + tr[18], c19 = readlane_f(score, 19) + tr[19];
        float c20 = readlane_f(score, 20) + tr[20];
        MRG(m0v, m0i, c0, 0, c1, 1)
        MRG(m1v, m1i, c2, 2, c3, 3)
        MRG(m2v, m2i, c4, 4, c5, 5)
        MRG(m3v, m3i, c6, 6, c7, 7)
        MRG(m4v, m4i, c8, 8, c9, 9)
        MRG(m5v, m5i, c10, 10, c11, 11)
        MRG(m6v, m6i, c12, 12, c13, 13)
        MRG(m7v, m7i, c14, 14, c15, 15)
        MRG(m8v, m8i, c16, 16, c17, 17)
        MRG(m9v, m9i, c18, 18, c19, 19)
        MRG(p0v, p0i, m0v, m0i, m1v, m1i)
        MRG(p1v, p1i, m2v, m2i, m3v, m3i)
        MRG(p2v, p2i, m4v, m4i, m5v, m5i)
        MRG(p3v, p3i, m6v, m6i, m7v, m7i)
        MRG(p4v, p4i, m8v, m8i, m9v, m9i)
        MRG(r0v, r0i, p0v, p0i, p1v, p1i)
        MRG(r1v, r1i, p2v, p2i, p3v, p3i)
        MRG(r2v, r2i, p4v, p4i, c20, 20)
        MRG(s0v, s0i, r0v, r0i, r1v, r1i)
        MRG(fv, fi, s0v, s0i, r2v, r2i)
        if (act) {
          hist_s[(t - 1) * K + j] = (unsigned char)fi;
          score = fv + em_s[t * K + j];
        }
      } else if (act) {
        hist_s[(t - 1) * K + j] = (unsigned char)j;
      }
    }
    if (act) sc_s[j] = score + endv[j];
    __syncthreads();
    if (j == 0) {
      float best = -3.0e38f;
      int cur = 0;
#pragma unroll
      for (int i = 0; i < K; i++)
        if (sc_s[i] > best) { best = sc_s[i]; cur = i; }
      outdec[b * T + (T - 1)] = (float)cur;
      for (int t = T - 1; t >= 1; t--) {
        cur = hist_s[(t - 1) * K + cur];
        outdec[b * T + (t - 1)] = (float)cur;
      }
    }
  }
}

__global__ void nll_final_kernel(const float* __restrict__ parts,
                                 float* __restrict__ out) {
  out[0] = -0.25f * (parts[0] + parts[1] + parts[2] + parts[3]);
}

// ---------------- host launcher ----------------
extern "C" void kernel_launch(void* const* d_in, const int* in_sizes, int n_in,
                              void* d_out, int out_size, void* d_ws, size_t ws_size,
                              hipStream_t stream) {
  (void)in_sizes; (void)n_in; (void)out_size; (void)ws_size;
  const int* ids    = (const int*)d_in[0];
  const int* amask  = (const int*)d_in[1];
  const int* labels = (const int*)d_in[3];
  const float* wemb = (const float*)d_in[4];
  const float* pemb = (const float*)d_in[5];
  const float* temb = (const float*)d_in[6];
  const float* eg   = (const float*)d_in[7];
  const float* ebta = (const float*)d_in[8];
  const float* Wqkv = (const float*)d_in[9];
  const float* bqkv = (const float*)d_in[10];
  const float* Wo   = (const float*)d_in[11];
  const float* bo   = (const float*)d_in[12];
  const float* ln1g = (const float*)d_in[13];
  const float* ln1b = (const float*)d_in[14];
  const float* W1   = (const float*)d_in[15];
  const float* b1   = (const float*)d_in[16];
  const float* W2   = (const float*)d_in[17];
  const float* b2   = (const float*)d_in[18];
  const float* ln2g = (const float*)d_in[19];
  const float* ln2b = (const float*)d_in[20];
  const float* Wc   = (const float*)d_in[21];
  const float* bc   = (const float*)d_in[22];
  const float* cst  = (const float*)d_in[23];
  const float* cen  = (const float*)d_in[24];
  const float* ctr  = (const float*)d_in[25];
  float* out = (float*)d_out;

  // workspace layout (float units)
  float* ws = (float*)d_ws;
  float* h    = ws;                                       // 1,572,864
  unsigned short* hh = (unsigned short*)(h + 1572864);
  unsigned short* hl = (unsigned short*)(h + 1572864 + 786432);
  float* qkv  = h + 1572864 + 786432 * 2;                 // 4,718,592
  unsigned short* cth = (unsigned short*)(qkv + 4718592);
  unsigned short* ctl = (unsigned short*)(qkv + 4718592 + 786432);
  float* tmp  = qkv + 4718592 + 786432 * 2;               // 1,572,864
  float* big  = tmp + 1572864;                            // 12,582,912 (scores)
  unsigned short* gh = (unsigned short*)(big + 12582912); // 2048*3072 u16
  unsigned short* gl = (unsigned short*)(big + 12582912 + 3145728);
  unsigned short* Wth = (unsigned short*)(big + 12582912 + 3145728 * 2);
  unsigned short* Wtl = (unsigned short*)(big + 12582912 + 3145728 * 2 + 3538944);
  float* em   = big + 12582912 + 3145728 * 2 + 3538944 * 2;
  float* parts = em + 43008;

  embed_ln_kernel<<<BT, 256, 0, stream>>>(ids, wemb, pemb, temb, eg, ebta, h, hh, hl);

  for (int l = 0; l < NLAYER; l++) {
    const float* bqkv_l = bqkv + (size_t)l * 3 * H;
    const float* bo_l   = bo + (size_t)l * H;
    const float* b1_l   = b1 + (size_t)l * 4 * H;
    const float* b2_l   = b2 + (size_t)l * H;

    wconv_kernel<<<6912, 256, 0, stream>>>(
        Wqkv + (size_t)l * H * 3 * H, Wo + (size_t)l * H * H,
        W1 + (size_t)l * H * 4 * H, W2 + (size_t)l * 4 * H * H, Wth, Wtl);

    gemm_bf3_kernel<128, false, false><<<dim3(18, 16), 256, 0, stream>>>(
        hh, hl, Wth, Wtl, bqkv_l, qkv, nullptr, nullptr, 3 * H, H);
    qk_kernel<<<dim3(T / 64, T / 64, B * NH), 256, 0, stream>>>(qkv, amask, big);
    softmax_kernel<<<B * NH * T, 128, 0, stream>>>(big);
    pv_kernel<<<dim3(T / 64, B * NH), 256, 0, stream>>>(big, qkv, cth, ctl);
    gemm_bf3_kernel<64, false, false><<<dim3(12, 16), 256, 0, stream>>>(
        cth, ctl, Wth + 1769472, Wtl + 1769472, bo_l, tmp, nullptr, nullptr, H, H);
    add_ln_kernel<<<BT, 256, 0, stream>>>(h, tmp, ln1g + (size_t)l * H, ln1b + (size_t)l * H, hh, hl);
    gemm_bf3_kernel<128, true, true><<<dim3(24, 16), 256, 0, stream>>>(
        hh, hl, Wth + 2359296, Wtl + 2359296, b1_l, nullptr, gh, gl, 4 * H, H);
    gemm_bf3_kernel<64, false, false><<<dim3(12, 16), 256, 0, stream>>>(
        gh, gl, Wth + 4718592, Wtl + 4718592, b2_l, tmp, nullptr, nullptr, H, 4 * H);
    add_ln_kernel<<<BT, 256, 0, stream>>>(h, tmp, ln2g + (size_t)l * H, ln2b + (size_t)l * H, hh, hl);
  }

  classifier_kernel<<<(BT * K + 255) / 256, 256, 0, stream>>>(h, Wc, bc, em);
  crf_fused_kernel<<<8, 64, 0, stream>>>(em, labels, amask, cst, cen, ctr, parts, out + 1);
  nll_final_kernel<<<1, 1, 0, stream>>>(parts, out);
}

// Round 6
// 3250.997 us; speedup vs baseline: 1.6117x; 1.0318x over previous
//
#include <hip/hip_runtime.h>
#include <math.h>

constexpr int NLAYER = 12;
constexpr int H = 768;
constexpr int NH = 12;
constexpr int DH = 64;
constexpr int T = 512;
constexpr int B = 4;
constexpr int K = 21;
constexpr int BT = B * T;
constexpr float NEGB = -10000.0f;
constexpr float LNEPS = 1e-12f;
constexpr float INV_SQRT_DH = 0.125f;

typedef __attribute__((ext_vector_type(8))) short bf16x8;
typedef __attribute__((ext_vector_type(4))) float f32x4;
typedef __attribute__((ext_vector_type(4))) unsigned short u16x4;

#define WAIT_VMCNT(n) asm volatile("s_waitcnt vmcnt(" #n ")")

// ---------------- helpers ----------------
__device__ __forceinline__ float wave_sum_f(float v) {
#pragma unroll
  for (int off = 32; off > 0; off >>= 1) v += __shfl_xor(v, off);
  return v;
}
__device__ __forceinline__ int wave_sum_i(int v) {
#pragma unroll
  for (int off = 32; off > 0; off >>= 1) v += __shfl_xor(v, off);
  return v;
}
__device__ __forceinline__ float readlane_f(float v, int i) {
  return __uint_as_float(__builtin_amdgcn_readlane(__float_as_uint(v), i));
}
__device__ __forceinline__ unsigned short f32_bf16_rn(float x) {
  unsigned int u = __float_as_uint(x);
  u += 0x7fffu + ((u >> 16) & 1u);
  return (unsigned short)(u >> 16);
}
__device__ __forceinline__ void split_bf16(float x, unsigned short& h, unsigned short& l) {
  h = f32_bf16_rn(x);
  float hf = __uint_as_float((unsigned int)h << 16);
  l = f32_bf16_rn(x - hf);
}
__device__ __forceinline__ void block_reduce_sum2(float& s, float& q) {
  __shared__ float red[8];
  s = wave_sum_f(s);
  q = wave_sum_f(q);
  int lane = threadIdx.x & 63, wid = threadIdx.x >> 6;
  if (lane == 0) { red[wid] = s; red[4 + wid] = q; }
  __syncthreads();
  s = red[0] + red[1] + red[2] + red[3];
  q = red[4] + red[5] + red[6] + red[7];
}

// ---------------- embedding + LN (emits f32 h and split bf16) ----------------
__global__ __launch_bounds__(256) void embed_ln_kernel(
    const int* __restrict__ ids, const float* __restrict__ wemb,
    const float* __restrict__ pemb, const float* __restrict__ temb,
    const float* __restrict__ g, const float* __restrict__ bta,
    float* __restrict__ h, unsigned short* __restrict__ hh,
    unsigned short* __restrict__ hl) {
  int row = blockIdx.x;
  int t = row % T;
  int id = ids[row];
  const float* wp = wemb + (size_t)id * H;
  const float* pp = pemb + (size_t)t * H;
  float x[3];
  float s = 0.f, q = 0.f;
#pragma unroll
  for (int i = 0; i < 3; i++) {
    int c = threadIdx.x + i * 256;
    x[i] = wp[c] + pp[c] + temb[c];
    s += x[i];
    q += x[i] * x[i];
  }
  block_reduce_sum2(s, q);
  float mean = s * (1.0f / H);
  float var = q * (1.0f / H) - mean * mean;
  float inv = rsqrtf(var + LNEPS);
#pragma unroll
  for (int i = 0; i < 3; i++) {
    int c = threadIdx.x + i * 256;
    float y = (x[i] - mean) * inv * g[c] + bta[c];
    h[(size_t)row * H + c] = y;
    unsigned short yh, yl;
    split_bf16(y, yh, yl);
    hh[(size_t)row * H + c] = yh;
    hl[(size_t)row * H + c] = yl;
  }
}

// ---------------- residual add + LN ----------------
__global__ __launch_bounds__(256) void add_ln_kernel(
    float* __restrict__ h, const float* __restrict__ add,
    const float* __restrict__ g, const float* __restrict__ bta,
    unsigned short* __restrict__ hh, unsigned short* __restrict__ hl) {
  int row = blockIdx.x;
  size_t base = (size_t)row * H;
  float x[3];
  float s = 0.f, q = 0.f;
#pragma unroll
  for (int i = 0; i < 3; i++) {
    int c = threadIdx.x + i * 256;
    x[i] = h[base + c] + add[base + c];
    s += x[i];
    q += x[i] * x[i];
  }
  block_reduce_sum2(s, q);
  float mean = s * (1.0f / H);
  float var = q * (1.0f / H) - mean * mean;
  float inv = rsqrtf(var + LNEPS);
#pragma unroll
  for (int i = 0; i < 3; i++) {
    int c = threadIdx.x + i * 256;
    float y = (x[i] - mean) * inv * g[c] + bta[c];
    h[base + c] = y;
    unsigned short yh, yl;
    split_bf16(y, yh, yl);
    hh[base + c] = yh;
    hl[base + c] = yl;
  }
}

// ---------------- per-layer weight transpose + split ----------------
__global__ __launch_bounds__(256) void wconv_kernel(
    const float* __restrict__ w0, const float* __restrict__ w1,
    const float* __restrict__ w2, const float* __restrict__ w3,
    unsigned short* __restrict__ Wth, unsigned short* __restrict__ Wtl) {
  __shared__ float tile[32][33];
  int bid = blockIdx.x;
  const float* src;
  int Kd, N, tk, tn;
  size_t off;
  if (bid < 1728) {
    src = w0; Kd = 768; N = 2304; tk = bid / 72; tn = bid % 72; off = 0;
  } else if (bid < 2304) {
    int t2 = bid - 1728; src = w1; Kd = 768; N = 768; tk = t2 / 24; tn = t2 % 24;
    off = 1769472;
  } else if (bid < 4608) {
    int t2 = bid - 2304; src = w2; Kd = 768; N = 3072; tk = t2 / 96; tn = t2 % 96;
    off = 2359296;
  } else {
    int t2 = bid - 4608; src = w3; Kd = 3072; N = 768; tk = t2 / 24; tn = t2 % 24;
    off = 4718592;
  }
  int tid = threadIdx.x;
  int k0 = tk * 32, n0 = tn * 32;
  int r = tid >> 3, c = (tid & 7) * 4;
  float4 v = *(const float4*)(src + (size_t)(k0 + r) * N + n0 + c);
  tile[r][c + 0] = v.x; tile[r][c + 1] = v.y; tile[r][c + 2] = v.z; tile[r][c + 3] = v.w;
  __syncthreads();
  u16x4 hv, lv;
#pragma unroll
  for (int q2 = 0; q2 < 4; q2++) {
    unsigned short sh, sl;
    split_bf16(tile[c + q2][r], sh, sl);
    hv[q2] = sh; lv[q2] = sl;
  }
  size_t dst = off + (size_t)(n0 + r) * Kd + k0 + c;
  *(u16x4*)(Wth + dst) = hv;
  *(u16x4*)(Wtl + dst) = lv;
}

// ---------------- bf16 3-term MFMA GEMM, 2-phase double-buffered ----------------
// LDS k-chunk swizzle: physical slot s of row r holds k-chunk s ^ ((r>>1)&3).
// Implemented via pre-swizzled global source (linear LDS dest for global_load_lds)
// and the matching XOR on the ds_read slot. Removes the 8-way bank conflict of
// the 64B-stride fragment reads (quarter-wave lanes now spread 8 bank-groups, 2-way).
template <int BN, bool GELU, bool SPLITOUT>
__global__ __launch_bounds__(256) void gemm_bf3_kernel(
    const unsigned short* __restrict__ Ah, const unsigned short* __restrict__ Al,
    const unsigned short* __restrict__ Wth, const unsigned short* __restrict__ Wtl,
    const float* __restrict__ bias, float* __restrict__ C,
    unsigned short* __restrict__ Ch, unsigned short* __restrict__ Cl,
    int N, int Kd) {
  constexpr int WN = BN / 2;
  constexpr int FN = WN / 16;
  constexpr int AW = 128 * 32;          // shorts per A tile
  constexpr int WW = BN * 32;           // shorts per W tile
  constexpr int DBS = 2 * AW + 2 * WW;  // shorts per buffer
  __shared__ short lds_s[2 * DBS];
  int tid = threadIdx.x;
  int lane = tid & 63, wid = tid >> 6;
  int wr = wid >> 1, wc = wid & 1;
  int bm = blockIdx.y * 128, bn = blockIdx.x * BN;
  f32x4 acc[4][FN] = {};
  int lrow = lane >> 2;
  int lslot_sw = (lane & 3) ^ ((lrow >> 1) & 3);   // source k-chunk for this lane's slot

  const unsigned short* sbase;
  int rowbase, ldsoff, nchunks;
  if (wid == 0)      { sbase = Ah;  rowbase = bm; ldsoff = 0;            nchunks = 8; }
  else if (wid == 1) { sbase = Al;  rowbase = bm; ldsoff = AW;           nchunks = 8; }
  else if (wid == 2) { sbase = Wth; rowbase = bn; ldsoff = 2 * AW;       nchunks = BN / 16; }
  else               { sbase = Wtl; rowbase = bn; ldsoff = 2 * AW + WW;  nchunks = BN / 16; }

  const unsigned short* srcbase = sbase + (size_t)(rowbase + lrow) * Kd + lslot_sw * 8;

  auto STAGE = [&](int db, int k0) {
#pragma unroll
    for (int c = 0; c < 8; c++) {
      if (c < nchunks) {
        const unsigned short* src = srcbase + (size_t)(c * 16) * Kd + k0;
        char* dst = ((char*)lds_s) + (db * DBS + ldsoff) * 2 + c * 1024 + lane * 16;
        __builtin_amdgcn_global_load_lds(
            (const __attribute__((address_space(1))) void*)src,
            (__attribute__((address_space(3))) void*)dst, 16, 0, 0);
      }
    }
  };

  const int NT = Kd / 32;
  STAGE(0, 0);
  for (int kt = 0; kt < NT; kt++) {
    int cur = kt & 1;
    bool more = (kt + 1 < NT);
    if (more) STAGE(cur ^ 1, (kt + 1) * 32);
    if (more) {
      if (BN == 128 || wid < 2) { WAIT_VMCNT(8); } else { WAIT_VMCNT(4); }
    } else {
      WAIT_VMCNT(0);
    }
    __builtin_amdgcn_s_barrier();
    __builtin_amdgcn_sched_barrier(0);

    int lr = lane & 15, lg = lane >> 4;
    int slot = (lg ^ ((lr >> 1) & 3)) * 8;  // swizzled read slot (shorts)
    int cb = cur * DBS;
    bf16x8 af_h[4], af_l[4], wf_h[FN], wf_l[FN];
#pragma unroll
    for (int i = 0; i < 4; i++) {
      int e = (wr * 64 + i * 16 + lr) * 32 + slot;
      af_h[i] = *(const bf16x8*)&lds_s[cb + e];
      af_l[i] = *(const bf16x8*)&lds_s[cb + AW + e];
    }
#pragma unroll
    for (int j = 0; j < FN; j++) {
      int e = (wc * WN + j * 16 + lr) * 32 + slot;
      wf_h[j] = *(const bf16x8*)&lds_s[cb + 2 * AW + e];
      wf_l[j] = *(const bf16x8*)&lds_s[cb + 2 * AW + WW + e];
    }
#pragma unroll
    for (int i = 0; i < 4; i++)
#pragma unroll
      for (int j = 0; j < FN; j++) {
        acc[i][j] = __builtin_amdgcn_mfma_f32_16x16x32_bf16(af_h[i], wf_h[j], acc[i][j], 0, 0, 0);
        acc[i][j] = __builtin_amdgcn_mfma_f32_16x16x32_bf16(af_l[i], wf_h[j], acc[i][j], 0, 0, 0);
        acc[i][j] = __builtin_amdgcn_mfma_f32_16x16x32_bf16(af_h[i], wf_l[j], acc[i][j], 0, 0, 0);
      }
    asm volatile("s_waitcnt lgkmcnt(0)");
    __builtin_amdgcn_sched_barrier(0);
    __builtin_amdgcn_s_barrier();   // buf[cur] free for next iteration's STAGE
    __builtin_amdgcn_sched_barrier(0);
  }

  int lr = lane & 15, lg = lane >> 4;
#pragma unroll
  for (int i = 0; i < 4; i++) {
#pragma unroll
    for (int j = 0; j < FN; j++) {
      int row = bm + wr * 64 + i * 16 + lg * 4;
      int col = bn + wc * WN + j * 16 + lr;
      float bv = bias[col];
#pragma unroll
      for (int r = 0; r < 4; r++) {
        float v = acc[i][j][r] + bv;
        if (GELU) v = 0.5f * v * (1.0f + erff(v * 0.70710678118654752f));
        if (SPLITOUT) {
          unsigned short sh, sl;
          split_bf16(v, sh, sl);
          Ch[(size_t)(row + r) * N + col] = sh;
          Cl[(size_t)(row + r) * N + col] = sl;
        } else {
          C[(size_t)(row + r) * N + col] = v;
        }
      }
    }
  }
}

// ---------------- S = Q K^T * scale + mask bias ----------------
__global__ __launch_bounds__(256) void qk_kernel(
    const float* __restrict__ qkv, const int* __restrict__ mask,
    float* __restrict__ S) {
  int bh = blockIdx.z;
  int b = bh / NH, hh = bh % NH;
  int i0 = blockIdx.y * 64, j0 = blockIdx.x * 64;
  __shared__ float Qs[64][64];
  __shared__ float Ks[64][64];
  int tid = threadIdx.x;
  int r = tid >> 2;
  int cseg = (tid & 3) * 16;
  const float* qbase = qkv + (size_t)(b * T + i0 + r) * (3 * H) + hh * DH;
  const float* kbase = qkv + (size_t)(b * T + j0 + r) * (3 * H) + H + hh * DH;
#pragma unroll
  for (int ss = 0; ss < 4; ss++) {
    int c = cseg + ss * 4;
    float4 qa = *(const float4*)(qbase + c);
    float4 ka = *(const float4*)(kbase + c);
    Qs[c + 0][r] = qa.x; Qs[c + 1][r] = qa.y; Qs[c + 2][r] = qa.z; Qs[c + 3][r] = qa.w;
    Ks[c + 0][r] = ka.x; Ks[c + 1][r] = ka.y; Ks[c + 2][r] = ka.z; Ks[c + 3][r] = ka.w;
  }
  __syncthreads();
  int tx = tid & 15, ty = tid >> 4;
  float acc[4][4] = {};
#pragma unroll 4
  for (int d = 0; d < 64; d++) {
    float a_[4], b_[4];
    *(float4*)a_ = *(const float4*)&Qs[d][ty * 4];
    *(float4*)b_ = *(const float4*)&Ks[d][tx * 4];
#pragma unroll
    for (int i = 0; i < 4; i++)
#pragma unroll
      for (int j = 0; j < 4; j++)
        acc[i][j] = fmaf(a_[i], b_[j], acc[i][j]);
  }
  float bj[4];
#pragma unroll
  for (int q = 0; q < 4; q++)
    bj[q] = (1.0f - (float)mask[b * T + j0 + tx * 4 + q]) * NEGB;
#pragma unroll
  for (int i = 0; i < 4; i++) {
    int gi = i0 + ty * 4 + i;
    int gj = j0 + tx * 4;
    float4 o;
    o.x = acc[i][0] * INV_SQRT_DH + bj[0];
    o.y = acc[i][1] * INV_SQRT_DH + bj[1];
    o.z = acc[i][2] * INV_SQRT_DH + bj[2];
    o.w = acc[i][3] * INV_SQRT_DH + bj[3];
    *(float4*)(S + ((size_t)bh * T + gi) * T + gj) = o;
  }
}

// ---------------- row softmax ----------------
__global__ __launch_bounds__(128) void softmax_kernel(float* __restrict__ S) {
  size_t row = blockIdx.x;
  float* p = S + row * T;
  int tid = threadIdx.x;
  float4 v = *(float4*)(p + tid * 4);
  float m = fmaxf(fmaxf(v.x, v.y), fmaxf(v.z, v.w));
#pragma unroll
  for (int off = 32; off > 0; off >>= 1) m = fmaxf(m, __shfl_xor(m, off));
  __shared__ float redm[2];
  __shared__ float reds[2];
  int wid = tid >> 6;
  if ((tid & 63) == 0) redm[wid] = m;
  __syncthreads();
  m = fmaxf(redm[0], redm[1]);
  v.x = __expf(v.x - m);
  v.y = __expf(v.y - m);
  v.z = __expf(v.z - m);
  v.w = __expf(v.w - m);
  float s = v.x + v.y + v.z + v.w;
  s = wave_sum_f(s);
  if ((tid & 63) == 0) reds[wid] = s;
  __syncthreads();
  s = reds[0] + reds[1];
  float inv = 1.0f / s;
  v.x *= inv; v.y *= inv; v.z *= inv; v.w *= inv;
  *(float4*)(p + tid * 4) = v;
}

// ---------------- ctx = P * V (emits split bf16 ctx) ----------------
__global__ __launch_bounds__(256) void pv_kernel(
    const float* __restrict__ S, const float* __restrict__ qkv,
    unsigned short* __restrict__ cth, unsigned short* __restrict__ ctl) {
  int bh = blockIdx.y;
  int b = bh / NH, hh = bh % NH;
  int i0 = blockIdx.x * 64;
  __shared__ float Ps[64][68];
  __shared__ float Vs[64][64];
  int tid = threadIdx.x;
  int r = tid >> 2;
  int cseg = (tid & 3) * 16;
  int tx = tid & 15, ty = tid >> 4;
  float acc[4][4] = {};
  const float* srow = S + ((size_t)bh * T + i0 + r) * T;
  const float* vbase = qkv + (size_t)(b * T) * (3 * H) + 2 * H + hh * DH;
  for (int k0 = 0; k0 < T; k0 += 64) {
    __syncthreads();
#pragma unroll
    for (int ss = 0; ss < 4; ss++) {
      int c = cseg + ss * 4;
      *(float4*)&Ps[r][c] = *(const float4*)(srow + k0 + c);
      *(float4*)&Vs[r][c] = *(const float4*)(vbase + (size_t)(k0 + r) * (3 * H) + c);
    }
    __syncthreads();
#pragma unroll
    for (int kk = 0; kk < 64; kk += 4) {
      float p_[4][4], v_[4][4];
#pragma unroll
      for (int i = 0; i < 4; i++)
        *(float4*)p_[i] = *(const float4*)&Ps[ty * 4 + i][kk];
#pragma unroll
      for (int s = 0; s < 4; s++)
        *(float4*)v_[s] = *(const float4*)&Vs[kk + s][tx * 4];
#pragma unroll
      for (int i = 0; i < 4; i++)
#pragma unroll
        for (int s = 0; s < 4; s++)
#pragma unroll
          for (int j = 0; j < 4; j++)
            acc[i][j] = fmaf(p_[i][s], v_[s][j], acc[i][j]);
    }
  }
#pragma unroll
  for (int i = 0; i < 4; i++) {
    int gi = i0 + ty * 4 + i;
    size_t idx = (size_t)(b * T + gi) * H + hh * DH + tx * 4;
    u16x4 hv, lv;
#pragma unroll
    for (int j = 0; j < 4; j++) {
      unsigned short sh, sl;
      split_bf16(acc[i][j], sh, sl);
      hv[j] = sh; lv[j] = sl;
    }
    *(u16x4*)(cth + idx) = hv;
    *(u16x4*)(ctl + idx) = lv;
  }
}

// ---------------- classifier ----------------
__global__ __launch_bounds__(256) void classifier_kernel(
    const float* __restrict__ h, const float* __restrict__ Wc,
    const float* __restrict__ bc, float* __restrict__ em) {
  int id = blockIdx.x * 256 + threadIdx.x;
  if (id >= BT * K) return;
  int row = id / K, k = id % K;
  float acc = bc[k];
  const float* hr = h + (size_t)row * H;
  for (int d = 0; d < H; d++) acc = fmaf(hr[d], Wc[d * K + k], acc);
  em[id] = acc;
}

// first-max merge (strict >, left/earlier index wins ties == jnp.argmax)
#define MRG(vo, io, va, ia, vb, ib) \
  float vo = ((vb) > (va)) ? (vb) : (va); \
  int io = ((vb) > (va)) ? (ib) : (ia);

// ---------------- fused CRF nll + viterbi (prefix-mask, prefetched em) ----------------
__global__ __launch_bounds__(64) void crf_fused_kernel(
    const float* __restrict__ em, const int* __restrict__ labels,
    const int* __restrict__ mask, const float* __restrict__ start,
    const float* __restrict__ endv, const float* __restrict__ trans,
    float* __restrict__ parts, float* __restrict__ outdec) {
  __shared__ float em_s[T * K];
  __shared__ int mask_s[T];
  __shared__ unsigned char hist_s[(T - 1) * K];
  __shared__ float sc_s[32];
  int b = blockIdx.x & 3;
  int role = blockIdx.x >> 2;
  int j = threadIdx.x;
  const float* eb = em + (size_t)b * T * K;
  for (int i = j; i < T * K / 4; i += 64)
    ((float4*)em_s)[i] = ((const float4*)eb)[i];
  for (int i = j; i < T; i += 64) mask_s[i] = mask[b * T + i];
  __syncthreads();
  bool act = (j < K);
  float tr[K];
#pragma unroll
  for (int i = 0; i < K; i++) tr[i] = act ? trans[i * K + j] : 0.f;

  // valid length (mask is a prefix: mask[t] = t < cnt)
  int cntloc = 0;
  for (int t = j; t < T; t += 64) cntloc += mask_s[t];
  int cnt = wave_sum_i(cntloc);

  if (role == 0) {
    // ---- numerator ----
    const int* tb = labels + b * T;
    float numloc = 0.f;
    for (int t = j; t < T; t += 64) {
      if (t >= 1 && mask_s[t]) {
        int tp = tb[t - 1], tc = tb[t];
        numloc += trans[tp * K + tc] + em_s[t * K + tc];
      }
    }
    float num = wave_sum_f(numloc);
    // ---- forward recursion: exp-factorized, readlane broadcast, em prefetch ----
    float etr[K];
#pragma unroll
    for (int i = 0; i < K; i++) etr[i] = __expf(tr[i]);
    float alpha = act ? (start[j] + em_s[j]) : 0.f;
    float emv = act ? em_s[K + j] : 0.f;
    for (int t = 1; t < cnt; t++) {
      float emv_n = (act && (t + 1) < cnt) ? em_s[(t + 1) * K + j] : 0.f;
      float m0 = readlane_f(alpha, 0);
      float ee = __expf(alpha - m0);
      float e0 = readlane_f(ee, 0),  e1 = readlane_f(ee, 1),  e2 = readlane_f(ee, 2);
      float e3 = readlane_f(ee, 3),  e4 = readlane_f(ee, 4),  e5 = readlane_f(ee, 5);
      float e6 = readlane_f(ee, 6),  e7 = readlane_f(ee, 7),  e8 = readlane_f(ee, 8);
      float e9 = readlane_f(ee, 9),  e10 = readlane_f(ee, 10), e11 = readlane_f(ee, 11);
      float e12 = readlane_f(ee, 12), e13 = readlane_f(ee, 13), e14 = readlane_f(ee, 14);
      float e15 = readlane_f(ee, 15), e16 = readlane_f(ee, 16), e17 = readlane_f(ee, 17);
      float e18 = readlane_f(ee, 18), e19 = readlane_f(ee, 19), e20 = readlane_f(ee, 20);
      float a0 = fmaf(e16, etr[16], fmaf(e12, etr[12], fmaf(e8, etr[8],  fmaf(e4, etr[4], e0 * etr[0]))));
      float a1 = fmaf(e17, etr[17], fmaf(e13, etr[13], fmaf(e9, etr[9],  fmaf(e5, etr[5], e1 * etr[1]))));
      float a2 = fmaf(e18, etr[18], fmaf(e14, etr[14], fmaf(e10, etr[10], fmaf(e6, etr[6], e2 * etr[2]))));
      float a3 = fmaf(e19, etr[19], fmaf(e15, etr[15], fmaf(e11, etr[11], fmaf(e7, etr[7], e3 * etr[3]))));
      float ssum = fmaf(e20, etr[20], (a0 + a1) + (a2 + a3));
      float nxt = __logf(ssum) + m0 + emv;
      if (act) alpha = nxt;
      emv = emv_n;
    }
    float aj = act ? (alpha + endv[j]) : -3.0e38f;
    float mm = aj;
#pragma unroll
    for (int off = 32; off > 0; off >>= 1) mm = fmaxf(mm, __shfl_xor(mm, off));
    float e2v = act ? __expf(aj - mm) : 0.f;
    float s2 = wave_sum_f(e2v);
    float den = __logf(s2) + mm;
    if (j == 0) {
      int tag0 = tb[0];
      float numtot = num + start[tag0] + em_s[tag0] + endv[tb[cnt - 1]];
      parts[b] = numtot - den;
    }
  } else {
    // ---- Viterbi: readlane broadcast + first-max tree, prefix-mask ----
    float score = act ? (start[j] + em_s[j]) : 0.f;
    float emv = act ? em_s[K + j] : 0.f;
    for (int t = 1; t < cnt; t++) {
      float emv_n = (act && (t + 1) < cnt) ? em_s[(t + 1) * K + j] : 0.f;
      float c0 = readlane_f(score, 0) + tr[0],   c1 = readlane_f(score, 1) + tr[1];
      float c2 = readlane_f(score, 2) + tr[2],   c3 = readlane_f(score, 3) + tr[3];
      float c4 = readlane_f(score, 4) + tr[4],   c5 = readlane_f(score, 5) + tr[5];
      float c6 = readlane_f(score, 6) + tr[6],   c7 = readlane_f(score, 7) + tr[7];
      float c8 = readlane_f(score, 8) + tr[8],   c9 = readlane_f(score, 9) + tr[9];
      float c10 = readlane_f(score, 10) + tr[10], c11 = readlane_f(score, 11) + tr[11];
      float c12 = readlane_f(score, 12) + tr[12], c13 = readlane_f(score, 13) + tr[13];
      float c14 = readlane_f(score, 14) + tr[14], c15 = readlane_f(score, 15) + tr[15];
      float c16 = readlane_f(score, 16) + tr[16], c17 = readlane_f(score, 17) + tr[17];
      float c18 = readlane_f(score, 18) + tr[18], c19 = readlane_f(score, 19) + tr[19];
      float c20 = readlane_f(score, 20) + tr[20];
      MRG(m0v, m0i, c0, 0, c1, 1)
      MRG(m1v, m1i, c2, 2, c3, 3)
      MRG(m2v, m2i, c4, 4, c5, 5)
      MRG(m3v, m3i, c6, 6, c7, 7)
      MRG(m4v, m4i, c8, 8, c9, 9)
      MRG(m5v, m5i, c10, 10, c11, 11)
      MRG(m6v, m6i, c12, 12, c13, 13)
      MRG(m7v, m7i, c14, 14, c15, 15)
      MRG(m8v, m8i, c16, 16, c17, 17)
      MRG(m9v, m9i, c18, 18, c19, 19)
      MRG(p0v, p0i, m0v, m0i, m1v, m1i)
      MRG(p1v, p1i, m2v, m2i, m3v, m3i)
      MRG(p2v, p2i, m4v, m4i, m5v, m5i)
      MRG(p3v, p3i, m6v, m6i, m7v, m7i)
      MRG(p4v, p4i, m8v, m8i, m9v, m9i)
      MRG(r0v, r0i, p0v, p0i, p1v, p1i)
      MRG(r1v, r1i, p2v, p2i, p3v, p3i)
      MRG(r2v, r2i, p4v, p4i, c20, 20)
      MRG(s0v, s0i, r0v, r0i, r1v, r1i)
      MRG(fv, fi, s0v, s0i, r2v, r2i)
      if (act) {
        hist_s[(t - 1) * K + j] = (unsigned char)fi;
        score = fv + emv;
      }
      emv = emv_n;
    }
    if (act) sc_s[j] = score + endv[j];
    __syncthreads();
    if (j == 0) {
      float best = -3.0e38f;
      int last = 0;
#pragma unroll
      for (int i = 0; i < K; i++)
        if (sc_s[i] > best) { best = sc_s[i]; last = i; }
      for (int t = cnt - 1; t < T; t++) outdec[b * T + t] = (float)last;
      int cur = last;
      for (int t = cnt - 1; t >= 1; t--) {
        cur = hist_s[(t - 1) * K + cur];
        outdec[b * T + (t - 1)] = (float)cur;
      }
    }
  }
}

__global__ void nll_final_kernel(const float* __restrict__ parts,
                                 float* __restrict__ out) {
  out[0] = -0.25f * (parts[0] + parts[1] + parts[2] + parts[3]);
}

// ---------------- host launcher ----------------
extern "C" void kernel_launch(void* const* d_in, const int* in_sizes, int n_in,
                              void* d_out, int out_size, void* d_ws, size_t ws_size,
                              hipStream_t stream) {
  (void)in_sizes; (void)n_in; (void)out_size; (void)ws_size;
  const int* ids    = (const int*)d_in[0];
  const int* amask  = (const int*)d_in[1];
  const int* labels = (const int*)d_in[3];
  const float* wemb = (const float*)d_in[4];
  const float* pemb = (const float*)d_in[5];
  const float* temb = (const float*)d_in[6];
  const float* eg   = (const float*)d_in[7];
  const float* ebta = (const float*)d_in[8];
  const float* Wqkv = (const float*)d_in[9];
  const float* bqkv = (const float*)d_in[10];
  const float* Wo   = (const float*)d_in[11];
  const float* bo   = (const float*)d_in[12];
  const float* ln1g = (const float*)d_in[13];
  const float* ln1b = (const float*)d_in[14];
  const float* W1   = (const float*)d_in[15];
  const float* b1   = (const float*)d_in[16];
  const float* W2   = (const float*)d_in[17];
  const float* b2   = (const float*)d_in[18];
  const float* ln2g = (const float*)d_in[19];
  const float* ln2b = (const float*)d_in[20];
  const float* Wc   = (const float*)d_in[21];
  const float* bc   = (const float*)d_in[22];
  const float* cst  = (const float*)d_in[23];
  const float* cen  = (const float*)d_in[24];
  const float* ctr  = (const float*)d_in[25];
  float* out = (float*)d_out;

  // workspace layout (float units)
  float* ws = (float*)d_ws;
  float* h    = ws;                                       // 1,572,864
  unsigned short* hh = (unsigned short*)(h + 1572864);
  unsigned short* hl = (unsigned short*)(h + 1572864 + 786432);
  float* qkv  = h + 1572864 + 786432 * 2;                 // 4,718,592
  unsigned short* cth = (unsigned short*)(qkv + 4718592);
  unsigned short* ctl = (unsigned short*)(qkv + 4718592 + 786432);
  float* tmp  = qkv + 4718592 + 786432 * 2;               // 1,572,864
  float* big  = tmp + 1572864;                            // 12,582,912 (scores)
  unsigned short* gh = (unsigned short*)(big + 12582912); // 2048*3072 u16
  unsigned short* gl = (unsigned short*)(big + 12582912 + 3145728);
  unsigned short* Wth = (unsigned short*)(big + 12582912 + 3145728 * 2);
  unsigned short* Wtl = (unsigned short*)(big + 12582912 + 3145728 * 2 + 3538944);
  float* em   = big + 12582912 + 3145728 * 2 + 3538944 * 2;
  float* parts = em + 43008;

  embed_ln_kernel<<<BT, 256, 0, stream>>>(ids, wemb, pemb, temb, eg, ebta, h, hh, hl);

  for (int l = 0; l < NLAYER; l++) {
    const float* bqkv_l = bqkv + (size_t)l * 3 * H;
    const float* bo_l   = bo + (size_t)l * H;
    const float* b1_l   = b1 + (size_t)l * 4 * H;
    const float* b2_l   = b2 + (size_t)l * H;

    wconv_kernel<<<6912, 256, 0, stream>>>(
        Wqkv + (size_t)l * H * 3 * H, Wo + (size_t)l * H * H,
        W1 + (size_t)l * H * 4 * H, W2 + (size_t)l * 4 * H * H, Wth, Wtl);

    gemm_bf3_kernel<128, false, false><<<dim3(18, 16), 256, 0, stream>>>(
        hh, hl, Wth, Wtl, bqkv_l, qkv, nullptr, nullptr, 3 * H, H);
    qk_kernel<<<dim3(T / 64, T / 64, B * NH), 256, 0, stream>>>(qkv, amask, big);
    softmax_kernel<<<B * NH * T, 128, 0, stream>>>(big);
    pv_kernel<<<dim3(T / 64, B * NH), 256, 0, stream>>>(big, qkv, cth, ctl);
    gemm_bf3_kernel<64, false, false><<<dim3(12, 16), 256, 0, stream>>>(
        cth, ctl, Wth + 1769472, Wtl + 1769472, bo_l, tmp, nullptr, nullptr, H, H);
    add_ln_kernel<<<BT, 256, 0, stream>>>(h, tmp, ln1g + (size_t)l * H, ln1b + (size_t)l * H, hh, hl);
    gemm_bf3_kernel<128, true, true><<<dim3(24, 16), 256, 0, stream>>>(
        hh, hl, Wth + 2359296, Wtl + 2359296, b1_l, nullptr, gh, gl, 4 * H, H);
    gemm_bf3_kernel<64, false, false><<<dim3(12, 16), 256, 0, stream>>>(
        gh, gl, Wth + 4718592, Wtl + 4718592, b2_l, tmp, nullptr, nullptr, H, 4 * H);
    add_ln_kernel<<<BT, 256, 0, stream>>>(h, tmp, ln2g + (size_t)l * H, ln2b + (size_t)l * H, hh, hl);
  }

  classifier_kernel<<<(BT * K + 255) / 256, 256, 0, stream>>>(h, Wc, bc, em);
  crf_fused_kernel<<<8, 64, 0, stream>>>(em, labels, amask, cst, cen, ctr, parts, out + 1);
  nll_final_kernel<<<1, 1, 0, stream>>>(parts, out);
}